// Round 3
// baseline (194.512 us; speedup 1.0000x reference)
//
#include <hip/hip_runtime.h>

typedef short s16x8 __attribute__((ext_vector_type(8)));
typedef float f32x4 __attribute__((ext_vector_type(4)));

__device__ __forceinline__ unsigned short bf16r(float f) {
  unsigned int u = __float_as_uint(f);
  u += 0x7fffu + ((u >> 16) & 1u);
  return (unsigned short)(u >> 16);
}

// ============================================================================
//                                FAST PATH
// ============================================================================

// ---- K1: fused adaptive-max-pool (50x50 -> 5x5) + x -> padded NHWC bf16 ----
// grid: 128 g * 5 bands = 640 blocks, 256 threads.
// xs layout: [g][yy 0..51][xx 0..51][i 0..63] bf16, yy=y+1, xx=x+1, borders 0.
__global__ __launch_bounds__(256) void poolprep_kernel(
    const float* __restrict__ x, float* __restrict__ pooled,
    unsigned short* __restrict__ xs) {
  const int blk = blockIdx.x;
  const int g = blk / 5, band = blk % 5;  // rows y in [band*10, band*10+10)
  const float* xg = x + (size_t)g * 160000;
  unsigned short* xsg = xs + (size_t)g * (52 * 52 * 64);
  __shared__ float pm[64 * 10 * 5];
  const int tid = threadIdx.x;

  // Phase A: transpose + bf16 convert. tasks (r,xpair,chunk) = 10*25*8 = 2000
  for (int task = tid; task < 2000; task += 256) {
    int chunk = task & 7;
    int rest = task >> 3;
    int xpair = rest % 25;
    int r = rest / 25;
    int y = band * 10 + r;
    const float* base = xg + (chunk * 8) * 2500 + y * 50 + xpair * 2;
    float2 v[8];
#pragma unroll
    for (int k = 0; k < 8; ++k) v[k] = *(const float2*)(base + k * 2500);
    uint4 a, b;
    a.x = (unsigned)bf16r(v[0].x) | ((unsigned)bf16r(v[1].x) << 16);
    a.y = (unsigned)bf16r(v[2].x) | ((unsigned)bf16r(v[3].x) << 16);
    a.z = (unsigned)bf16r(v[4].x) | ((unsigned)bf16r(v[5].x) << 16);
    a.w = (unsigned)bf16r(v[6].x) | ((unsigned)bf16r(v[7].x) << 16);
    b.x = (unsigned)bf16r(v[0].y) | ((unsigned)bf16r(v[1].y) << 16);
    b.y = (unsigned)bf16r(v[2].y) | ((unsigned)bf16r(v[3].y) << 16);
    b.z = (unsigned)bf16r(v[4].y) | ((unsigned)bf16r(v[5].y) << 16);
    b.w = (unsigned)bf16r(v[6].y) | ((unsigned)bf16r(v[7].y) << 16);
    int xx = xpair * 2;
    *(uint4*)&xsg[(((y + 1) * 52) + (xx + 1)) * 64 + chunk * 8] = a;
    *(uint4*)&xsg[(((y + 1) * 52) + (xx + 2)) * 64 + chunk * 8] = b;
  }
  // Border zeros: cols 0 and 51 for this band's 10 rows: 10*2*8 = 160 tasks
  uint4 z4;
  z4.x = 0; z4.y = 0; z4.z = 0; z4.w = 0;
  for (int task = tid; task < 160; task += 256) {
    int chunk = task & 7;
    int rest = task >> 3;
    int col = (rest & 1) ? 51 : 0;
    int r = rest >> 1;
    int y = band * 10 + r;
    *(uint4*)&xsg[(((y + 1) * 52) + col) * 64 + chunk * 8] = z4;
  }
  if (band == 0) {  // row 0: 52*8 = 416 tasks
    for (int task = tid; task < 416; task += 256)
      *(uint4*)&xsg[(task >> 3) * 64 + (task & 7) * 8] = z4;
  }
  if (band == 4) {  // row 51
    for (int task = tid; task < 416; task += 256)
      *(uint4*)&xsg[(51 * 52 + (task >> 3)) * 64 + (task & 7) * 8] = z4;
  }

  // Phase B: pool partials. tasks (c,r) = 640; L2-hot re-read of this slab.
  for (int task = tid; task < 640; task += 256) {
    int r = task % 10;
    int c = task / 10;
    const float2* row = (const float2*)(xg + c * 2500 + (band * 10 + r) * 50);
#pragma unroll
    for (int ox = 0; ox < 5; ++ox) {
      float2 v0 = row[ox * 5 + 0], v1 = row[ox * 5 + 1], v2 = row[ox * 5 + 2];
      float2 v3 = row[ox * 5 + 3], v4 = row[ox * 5 + 4];
      float m = fmaxf(fmaxf(fmaxf(v0.x, v0.y), fmaxf(v1.x, v1.y)),
                      fmaxf(fmaxf(v2.x, v2.y), fmaxf(v3.x, v3.y)));
      m = fmaxf(m, fmaxf(v4.x, v4.y));
      pm[(c * 10 + r) * 5 + ox] = m;
    }
  }
  __syncthreads();
  // BUGFIX (round 2): 320 tasks > 256 threads -> must loop, not `if (tid<320)`
  for (int t2 = tid; t2 < 320; t2 += 256) {
    int ox = t2 % 5, c = t2 / 5;
    float m = pm[(c * 10) * 5 + ox];
#pragma unroll
    for (int r = 1; r < 10; ++r) m = fmaxf(m, pm[(c * 10 + r) * 5 + ox]);
    pooled[(size_t)g * 1600 + c * 25 + band * 5 + ox] = m;
  }
}

// ---- wscale: per-group scaled weights in MFMA A-fragment order -------------
// wt3[g] flat: ((((tap*2+ik)*4+mf)*64)+lane)*8 + j ; value W[o][i][tap]*scale[g][i]
__global__ __launch_bounds__(256) void wscale_kernel(
    const float* __restrict__ w, const float* __restrict__ scale_g,
    unsigned short* __restrict__ wt3) {
  const int g = blockIdx.x;
  const int tid = threadIdx.x;
  __shared__ float sc[64];
  if (tid < 64) sc[tid] = scale_g[g * 64 + tid];
  __syncthreads();
  unsigned short* outg = wt3 + (size_t)g * 36864;
  for (int idx = tid; idx < 36864; idx += 256) {
    int j = idx & 7;
    int lane = (idx >> 3) & 63;
    int mf = (idx >> 9) & 3;
    int ik = (idx >> 11) & 1;
    int tap = idx >> 12;
    int o = mf * 16 + (lane & 15);
    int i = ik * 32 + 8 * (lane >> 4) + j;
    outg[idx] = bf16r(w[((o * 64) + i) * 9 + tap] * sc[i]);
  }
}

// ---- conv_main_fast: DMA-staged MFMA conv --------------------------------
// out[g,o,y,x] = sum_{i,dy,dx} xs[g,y+dy,x+dx,i] * wt3[g][o,i,tap] + fb[g,o]
__global__ __launch_bounds__(256) void conv_main_fast(
    const unsigned short* __restrict__ xs, const unsigned short* __restrict__ wt3,
    const float* __restrict__ fb_g, float* __restrict__ out) {
  const int g = blockIdx.x & 127;    // 13 bands of one g land on the same XCD
  const int band = blockIdx.x >> 7;  // 0..12
  const int y0 = band * 4;
  const int tid = threadIdx.x;
  __shared__ unsigned short in_s[6 * 66 * 64];
  __shared__ float fb_s[64];
  if (tid < 64) fb_s[tid] = fb_g[g * 64 + tid];

  // stage via global_load_lds: LDS linear in task order = [r][c][chunk][8],
  // source chunk pre-swizzled (chunk ^ (c&7)); borders are true zeros in xs,
  // OOB rows/cols (py>=52, c>=52) only feed discarded output lanes.
  const unsigned short* xsg = xs + (size_t)g * (52 * 52 * 64);
  for (int task = tid; task < 3168; task += 256) {
    int chunk = task & 7;
    int c = (task >> 3) % 66;
    int r = (task >> 3) / 66;
    int py = y0 + r;  // padded row
    int srcChunk = chunk ^ (c & 7);
    const unsigned short* src = xsg + ((size_t)(py * 52 + c) * 64 + srcChunk * 8);
    unsigned short* ldsb = in_s + (size_t)(task & ~63) * 8;
    __builtin_amdgcn_global_load_lds(
        (const __attribute__((address_space(1))) void*)src,
        (__attribute__((address_space(3))) void*)ldsb, 16, 0, 0);
  }
  __syncthreads();

  const int wave = tid >> 6, lane = tid & 63;
  const int l15 = lane & 15, l4 = lane >> 4;
  const int yrow = y0 + wave;
  if (yrow < 50) {
    f32x4 acc[4][4];
    f32x4 z = {0.f, 0.f, 0.f, 0.f};
#pragma unroll
    for (int mf = 0; mf < 4; ++mf)
#pragma unroll
      for (int nf = 0; nf < 4; ++nf) acc[mf][nf] = z;

    const unsigned short* wg = wt3 + (size_t)g * 36864;
#pragma unroll
    for (int dy = 0; dy < 3; ++dy) {
      const int rr = wave + dy;
#pragma unroll
      for (int dx = 0; dx < 3; ++dx) {
        const int tap = dy * 3 + dx;
#pragma unroll
        for (int ik = 0; ik < 2; ++ik) {
          s16x8 a[4], bfr[4];
#pragma unroll
          for (int mf = 0; mf < 4; ++mf)
            a[mf] = *reinterpret_cast<const s16x8*>(
                wg + ((((tap * 2 + ik) * 4 + mf) * 64 + lane) << 3));
#pragma unroll
          for (int nf = 0; nf < 4; ++nf) {
            int cc = nf * 16 + l15 + dx;
            int chS = (ik * 4 + l4) ^ (cc & 7);
            bfr[nf] = *reinterpret_cast<const s16x8*>(
                &in_s[((rr * 66 + cc) << 6) + (chS << 3)]);
          }
#pragma unroll
          for (int mf = 0; mf < 4; ++mf)
#pragma unroll
            for (int nf = 0; nf < 4; ++nf)
              acc[mf][nf] = __builtin_amdgcn_mfma_f32_16x16x32_bf16(
                  a[mf], bfr[nf], acc[mf][nf], 0, 0, 0);
        }
      }
    }
    float* og = out + (size_t)g * 64 * 2500 + yrow * 50;
#pragma unroll
    for (int mf = 0; mf < 4; ++mf) {
#pragma unroll
      for (int r = 0; r < 4; ++r) {
        int o = mf * 16 + l4 * 4 + r;
        float fbv = fb_s[o];
#pragma unroll
        for (int nf = 0; nf < 4; ++nf) {
          int xx = nf * 16 + l15;
          if (xx < 50) og[(size_t)o * 2500 + xx] = acc[mf][nf][r] + fbv;
        }
      }
    }
  }
}

// ============================================================================
//                       LEGACY (round-1) PATH — fallback
// ============================================================================

__global__ __launch_bounds__(256) void pool_kernel(const float* __restrict__ x,
                                                   float* __restrict__ pooled) {
  const int blk = blockIdx.x;
  const float* plane = x + (size_t)blk * 2500;
  __shared__ float pmax[250];
  const int t = threadIdx.x;
  if (t < 250) {
    int r = t / 5, cc = t % 5;
    const float* row = plane + r * 50 + cc * 10;
    float m = row[0];
#pragma unroll
    for (int j = 1; j < 10; ++j) m = fmaxf(m, row[j]);
    pmax[r * 5 + cc] = m;
  }
  __syncthreads();
  if (t < 25) {
    int pr = t / 5, cc = t % 5;
    float m = pmax[(pr * 10) * 5 + cc];
#pragma unroll
    for (int rr = 1; rr < 10; ++rr) m = fmaxf(m, pmax[(pr * 10 + rr) * 5 + cc]);
    pooled[(size_t)blk * 25 + t] = m;
  }
}

__global__ __launch_bounds__(256) void wt_kernel(const float* __restrict__ w,
                                                 unsigned short* __restrict__ wt2) {
  int idx = blockIdx.x * 256 + threadIdx.x;
  if (idx >= 36864) return;
  int j = idx & 7;
  int lane = (idx >> 3) & 63;
  int mf = (idx >> 9) & 3;
  int ik = (idx >> 11) & 1;
  int tap = idx >> 12;
  int o = mf * 16 + (lane & 15);
  int i = ik * 32 + 8 * (lane >> 4) + j;
  wt2[idx] = bf16r(w[((o * 64) + i) * 9 + tap]);
}

__global__ __launch_bounds__(256) void conv_main(
    const float* __restrict__ x, const unsigned short* __restrict__ wt2,
    const float* __restrict__ scale_g, const float* __restrict__ fb_g,
    float* __restrict__ out) {
  const int g = blockIdx.x & 127;
  const int band = blockIdx.x >> 7;
  const int y0 = band * 4;
  const int tid = threadIdx.x;
  __shared__ unsigned short in_s[6 * 66 * 64];
  __shared__ float scale_s[64], fb_s[64];
  if (tid < 64) {
    scale_s[tid] = scale_g[g * 64 + tid];
    fb_s[tid] = fb_g[g * 64 + tid];
  }
  __syncthreads();
  const float* xg = x + (size_t)g * 160000;
  for (int task = tid; task < 3168; task += 256) {
    int c = task % 66;
    int rc = task / 66;
    int r = rc >> 3;
    int chunk = rc & 7;
    int y = y0 - 1 + r;
    int xi = c - 1;
    unsigned int p0 = 0, p1 = 0, p2 = 0, p3 = 0;
    if (y >= 0 && y < 50 && xi >= 0 && xi < 50) {
      const float* px = xg + chunk * 8 * 2500 + y * 50 + xi;
      float f0 = px[0] * scale_s[chunk * 8 + 0];
      float f1 = px[2500] * scale_s[chunk * 8 + 1];
      float f2 = px[5000] * scale_s[chunk * 8 + 2];
      float f3 = px[7500] * scale_s[chunk * 8 + 3];
      float f4 = px[10000] * scale_s[chunk * 8 + 4];
      float f5 = px[12500] * scale_s[chunk * 8 + 5];
      float f6 = px[15000] * scale_s[chunk * 8 + 6];
      float f7 = px[17500] * scale_s[chunk * 8 + 7];
      p0 = (unsigned)bf16r(f0) | ((unsigned)bf16r(f1) << 16);
      p1 = (unsigned)bf16r(f2) | ((unsigned)bf16r(f3) << 16);
      p2 = (unsigned)bf16r(f4) | ((unsigned)bf16r(f5) << 16);
      p3 = (unsigned)bf16r(f6) | ((unsigned)bf16r(f7) << 16);
    }
    int chS = chunk ^ (c & 7);
    uint4* dst = (uint4*)&in_s[((r * 66 + c) << 6) + (chS << 3)];
    uint4 u4;
    u4.x = p0; u4.y = p1; u4.z = p2; u4.w = p3;
    *dst = u4;
  }
  __syncthreads();
  const int wave = tid >> 6, lane = tid & 63;
  const int l15 = lane & 15, l4 = lane >> 4;
  const int yrow = y0 + wave;
  if (yrow < 50) {
    f32x4 acc[4][4];
    f32x4 z = {0.f, 0.f, 0.f, 0.f};
#pragma unroll
    for (int mf = 0; mf < 4; ++mf)
#pragma unroll
      for (int nf = 0; nf < 4; ++nf) acc[mf][nf] = z;
#pragma unroll
    for (int dy = 0; dy < 3; ++dy) {
      const int rr = wave + dy;
#pragma unroll
      for (int dx = 0; dx < 3; ++dx) {
        const int tap = dy * 3 + dx;
#pragma unroll
        for (int ik = 0; ik < 2; ++ik) {
          s16x8 a[4], bfr[4];
#pragma unroll
          for (int mf = 0; mf < 4; ++mf)
            a[mf] = *reinterpret_cast<const s16x8*>(
                wt2 + ((((tap * 2 + ik) * 4 + mf) * 64 + lane) << 3));
#pragma unroll
          for (int nf = 0; nf < 4; ++nf) {
            int cc = nf * 16 + l15 + dx;
            int chS = (ik * 4 + l4) ^ (cc & 7);
            bfr[nf] = *reinterpret_cast<const s16x8*>(
                &in_s[((rr * 66 + cc) << 6) + (chS << 3)]);
          }
#pragma unroll
          for (int mf = 0; mf < 4; ++mf)
#pragma unroll
            for (int nf = 0; nf < 4; ++nf)
              acc[mf][nf] = __builtin_amdgcn_mfma_f32_16x16x32_bf16(
                  a[mf], bfr[nf], acc[mf][nf], 0, 0, 0);
        }
      }
    }
    float* og = out + (size_t)g * 64 * 2500 + yrow * 50;
#pragma unroll
    for (int mf = 0; mf < 4; ++mf) {
#pragma unroll
      for (int r = 0; r < 4; ++r) {
        int o = mf * 16 + l4 * 4 + r;
        float fbv = fb_s[o];
#pragma unroll
        for (int nf = 0; nf < 4; ++nf) {
          int xx = nf * 16 + l15;
          if (xx < 50) og[(size_t)o * 2500 + xx] = acc[mf][nf][r] + fbv;
        }
      }
    }
  }
}

// ============================================================================
//                      shared: convB + scan (unchanged)
// ============================================================================

__device__ __forceinline__ void conv64(const float* pool_s, const float* __restrict__ wgt,
                                       const float* __restrict__ bias, float* red,
                                       float* __restrict__ outg, int tid) {
  int co = tid & 63, qd = tid >> 6;
  float acc[25];
#pragma unroll
  for (int n = 0; n < 25; ++n) acc[n] = 0.f;
  for (int ci = qd * 16; ci < qd * 16 + 16; ++ci) {
    float in[25];
#pragma unroll
    for (int n = 0; n < 25; ++n) in[n] = pool_s[ci * 25 + n];
    float w9[9];
#pragma unroll
    for (int tp = 0; tp < 9; ++tp) w9[tp] = wgt[(co * 64 + ci) * 9 + tp];
#pragma unroll
    for (int n = 0; n < 25; ++n) {
      int y = n / 5, xx = n % 5;
#pragma unroll
      for (int dy = 0; dy < 3; ++dy) {
        int yy = y + dy - 1;
        if (yy < 0 || yy > 4) continue;
#pragma unroll
        for (int dx = 0; dx < 3; ++dx) {
          int xc = xx + dx - 1;
          if (xc < 0 || xc > 4) continue;
          acc[n] += in[yy * 5 + xc] * w9[dy * 3 + dx];
        }
      }
    }
  }
#pragma unroll
  for (int n = 0; n < 25; ++n) red[(qd * 64 + co) * 25 + n] = acc[n];
  __syncthreads();
  for (int idx = tid; idx < 1600; idx += 256) {
    float s = red[idx] + red[1600 + idx] + red[3200 + idx] + red[4800 + idx];
    outg[idx] = s + bias[idx / 25];
  }
  __syncthreads();
}

__device__ __forceinline__ void conv4(const float* pool_s, const float* __restrict__ wgt,
                                      const float* __restrict__ bias, float* red,
                                      float* __restrict__ outg, int tid) {
  int co = tid & 3, ci = tid >> 2;
  float acc[25];
#pragma unroll
  for (int n = 0; n < 25; ++n) acc[n] = 0.f;
  float in[25];
#pragma unroll
  for (int n = 0; n < 25; ++n) in[n] = pool_s[ci * 25 + n];
  float w9[9];
#pragma unroll
  for (int tp = 0; tp < 9; ++tp) w9[tp] = wgt[(co * 64 + ci) * 9 + tp];
#pragma unroll
  for (int n = 0; n < 25; ++n) {
    int y = n / 5, xx = n % 5;
#pragma unroll
    for (int dy = 0; dy < 3; ++dy) {
      int yy = y + dy - 1;
      if (yy < 0 || yy > 4) continue;
#pragma unroll
      for (int dx = 0; dx < 3; ++dx) {
        int xc = xx + dx - 1;
        if (xc < 0 || xc > 4) continue;
        acc[n] += in[yy * 5 + xc] * w9[dy * 3 + dx];
      }
    }
  }
#pragma unroll
  for (int n = 0; n < 25; ++n) red[(ci * 4 + co) * 25 + n] = acc[n];
  __syncthreads();
  if (tid < 100) {
    int co2 = tid / 25, n = tid % 25;
    float s = 0.f;
    for (int c = 0; c < 64; ++c) s += red[(c * 4 + co2) * 25 + n];
    outg[co2 * 25 + n] = s + bias[co2];
  }
  __syncthreads();
}

__global__ __launch_bounds__(256) void convB_kernel(
    const float* __restrict__ pooled, const float* __restrict__ vw,
    const float* __restrict__ vb, const float* __restrict__ kw,
    const float* __restrict__ kb, const float* __restrict__ iw,
    const float* __restrict__ ib, float* __restrict__ vconv,
    float* __restrict__ kconv, float* __restrict__ prior0) {
  const int blk = blockIdx.x;
  __shared__ float pool_s[1600];
  __shared__ float red[6400];
  const int tid = threadIdx.x;
  for (int idx = tid; idx < 1600; idx += 256) pool_s[idx] = pooled[blk * 1600 + idx];
  __syncthreads();
  conv64(pool_s, vw, vb, red, vconv + blk * 1600, tid);
  conv4(pool_s, kw, kb, red, kconv + blk * 100, tid);
  if ((blk & 7) == 0) conv64(pool_s, iw, ib, red, prior0 + (blk >> 3) * 1600, tid);
}

__global__ __launch_bounds__(256) void scan_kernel(
    const float* __restrict__ vconv, const float* __restrict__ kconv,
    const float* __restrict__ prior0, const float* __restrict__ qw,
    const float* __restrict__ qb, const float* __restrict__ tconvw,
    const float* __restrict__ tconvb, const float* __restrict__ fcw,
    const float* __restrict__ fcb, const float* __restrict__ bias,
    float* __restrict__ scale_g, float* __restrict__ fb_g) {
  const int b = blockIdx.x;
  const int tid = threadIdx.x;
  __shared__ float p_s[1600], v_s[1600], kk_s[100], q_s[100];
  __shared__ float qw_s[2304];
  __shared__ float tcw_s[64 * 65];
  __shared__ float attn_s[625];
  __shared__ float red[6400];
  __shared__ float avg_s[64];

  for (int idx = tid; idx < 1600; idx += 256) p_s[idx] = prior0[b * 1600 + idx];
  for (int idx = tid; idx < 2304; idx += 256) qw_s[idx] = qw[idx];
  for (int idx = tid; idx < 4096; idx += 256) tcw_s[(idx / 64) * 65 + (idx % 64)] = tconvw[idx];
  __syncthreads();

  const int qco = tid & 3, qci = tid >> 2;
  float qwr[9];
#pragma unroll
  for (int tp = 0; tp < 9; ++tp) qwr[tp] = qw_s[(qco * 64 + qci) * 9 + tp];

  for (int l = 0; l < 8; ++l) {
    const int bl = b * 8 + l;
    for (int idx = tid; idx < 1600; idx += 256) v_s[idx] = vconv[bl * 1600 + idx];
    if (tid < 100) kk_s[tid] = kconv[bl * 100 + tid];
    __syncthreads();
    {
      float in[25];
#pragma unroll
      for (int n = 0; n < 25; ++n) in[n] = p_s[qci * 25 + n];
      float acc[25];
#pragma unroll
      for (int n = 0; n < 25; ++n) acc[n] = 0.f;
#pragma unroll
      for (int n = 0; n < 25; ++n) {
        int y = n / 5, xx = n % 5;
#pragma unroll
        for (int dy = 0; dy < 3; ++dy) {
          int yy = y + dy - 1;
          if (yy < 0 || yy > 4) continue;
#pragma unroll
          for (int dx = 0; dx < 3; ++dx) {
            int xc = xx + dx - 1;
            if (xc < 0 || xc > 4) continue;
            acc[n] += in[yy * 5 + xc] * qwr[dy * 3 + dx];
          }
        }
      }
#pragma unroll
      for (int n = 0; n < 25; ++n) red[(qci * 4 + qco) * 25 + n] = acc[n];
    }
    __syncthreads();
    if (tid < 100) {
      int co = tid / 25, n = tid % 25;
      float s = qb[co];
      for (int c = 0; c < 64; ++c) s += red[(c * 4 + co) * 25 + n];
      q_s[co * 25 + n] = s;
    }
    __syncthreads();
    for (int idx = tid; idx < 625; idx += 256) {
      int n = idx / 25, m = idx % 25;
      float s = 0.f;
#pragma unroll
      for (int c = 0; c < 4; ++c) s += q_s[c * 25 + n] * kk_s[c * 25 + m];
      attn_s[idx] = s;
    }
    __syncthreads();
    if (tid < 25) {
      float* row = attn_s + tid * 25;
      float mx = row[0];
#pragma unroll
      for (int m = 1; m < 25; ++m) mx = fmaxf(mx, row[m]);
      float sm = 0.f;
#pragma unroll
      for (int m = 0; m < 25; ++m) {
        float e = __expf(row[m] - mx);
        row[m] = e;
        sm += e;
      }
      float inv = 1.0f / sm;
#pragma unroll
      for (int m = 0; m < 25; ++m) row[m] *= inv;
    }
    __syncthreads();
    if (tid < 200) {
      int n = tid % 25, cc = tid / 25;
      float ar[25];
#pragma unroll
      for (int m = 0; m < 25; ++m) ar[m] = attn_s[n * 25 + m];
#pragma unroll
      for (int cj = 0; cj < 8; ++cj) {
        int c = cc * 8 + cj;
        float s = 0.f;
#pragma unroll
        for (int m = 0; m < 25; ++m) s += v_s[c * 25 + m] * ar[m];
        p_s[c * 25 + n] = s;
      }
    }
    __syncthreads();
    if (tid < 64) {
      float s = 0.f;
#pragma unroll
      for (int n = 0; n < 25; ++n) s += p_s[tid * 25 + n];
      avg_s[tid] = s * 0.04f;
    }
    __syncthreads();
    if (tid < 64) {
      int o = tid;
      float cal = tconvb[o];
      for (int c = 0; c < 64; ++c) cal += tcw_s[o * 65 + c] * avg_s[c];
      scale_g[bl * 64 + o] = 1.0f + cal;
      float part = fcw[o] * avg_s[o];
#pragma unroll
      for (int off = 32; off; off >>= 1) part += __shfl_down(part, off);
      float fc = __shfl(part, 0) + fcb[0];
      fb_g[bl * 64 + o] = bias[o] * (1.0f + fc);
    }
    __syncthreads();
  }
}

// --------------------------------- launch ---------------------------------
extern "C" void kernel_launch(void* const* d_in, const int* in_sizes, int n_in,
                              void* d_out, int out_size, void* d_ws, size_t ws_size,
                              hipStream_t stream) {
  const float* x       = (const float*)d_in[0];
  const float* weight  = (const float*)d_in[1];
  const float* bias    = (const float*)d_in[2];
  const float* init_w  = (const float*)d_in[3];
  const float* init_b  = (const float*)d_in[4];
  const float* q_w     = (const float*)d_in[5];
  const float* q_b     = (const float*)d_in[6];
  const float* k_w     = (const float*)d_in[7];
  const float* k_b     = (const float*)d_in[8];
  const float* v_w     = (const float*)d_in[9];
  const float* v_b     = (const float*)d_in[10];
  const float* tconv_w = (const float*)d_in[11];
  const float* tconv_b = (const float*)d_in[12];
  const float* fc_w    = (const float*)d_in[13];
  const float* fc_b    = (const float*)d_in[14];
  float* out = (float*)d_out;

  float* ws = (float*)d_ws;
  float* pooled = ws;                  // 204800 f
  float* vconv  = ws + 204800;         // 204800 f
  float* kconv  = ws + 409600;         // 12800 f
  float* prior0 = ws + 422400;         // 25600 f
  float* scaleg = ws + 448000;         // 8192 f
  float* fbg    = ws + 456192;         // 8192 f
  unsigned short* wt3 = (unsigned short*)(ws + 464384);   // 4718592 us
  unsigned short* xsb = wt3 + 4718592;                    // 22151168 us

  const size_t NEED_FAST = 55662592ull;  // floats + wt3 + xs + 64KB OOB slack

  if (ws_size >= NEED_FAST) {
    poolprep_kernel<<<640, 256, 0, stream>>>(x, pooled, xsb);
    convB_kernel<<<128, 256, 0, stream>>>(pooled, v_w, v_b, k_w, k_b, init_w, init_b,
                                          vconv, kconv, prior0);
    scan_kernel<<<16, 256, 0, stream>>>(vconv, kconv, prior0, q_w, q_b, tconv_w,
                                        tconv_b, fc_w, fc_b, bias, scaleg, fbg);
    wscale_kernel<<<128, 256, 0, stream>>>(weight, scaleg, wt3);
    conv_main_fast<<<13 * 128, 256, 0, stream>>>(xsb, wt3, fbg, out);
  } else {
    unsigned short* wt2 = (unsigned short*)(ws + 464384);
    pool_kernel<<<8192, 256, 0, stream>>>(x, pooled);
    wt_kernel<<<144, 256, 0, stream>>>(weight, wt2);
    convB_kernel<<<128, 256, 0, stream>>>(pooled, v_w, v_b, k_w, k_b, init_w, init_b,
                                          vconv, kconv, prior0);
    scan_kernel<<<16, 256, 0, stream>>>(vconv, kconv, prior0, q_w, q_b, tconv_w,
                                        tconv_b, fc_w, fc_b, bias, scaleg, fbg);
    conv_main<<<13 * 128, 256, 0, stream>>>(x, wt2, scaleg, fbg, out);
  }
}

// Round 4
// 186.567 us; speedup vs baseline: 1.0426x; 1.0426x over previous
//
#include <hip/hip_runtime.h>

typedef short s16x8 __attribute__((ext_vector_type(8)));
typedef float f32x4 __attribute__((ext_vector_type(4)));

__device__ __forceinline__ unsigned short bf16r(float f) {
  unsigned int u = __float_as_uint(f);
  u += 0x7fffu + ((u >> 16) & 1u);
  return (unsigned short)(u >> 16);
}

// ============================================================================
//                                FAST PATH
// ============================================================================

// ---- K1: fused adaptive-max-pool (50x50 -> 5x5) + x -> padded NHWC bf16 ----
__global__ __launch_bounds__(256) void poolprep_kernel(
    const float* __restrict__ x, float* __restrict__ pooled,
    unsigned short* __restrict__ xs) {
  const int blk = blockIdx.x;
  const int g = blk / 5, band = blk % 5;  // rows y in [band*10, band*10+10)
  const float* xg = x + (size_t)g * 160000;
  unsigned short* xsg = xs + (size_t)g * (52 * 52 * 64);
  __shared__ float pm[64 * 10 * 5];
  const int tid = threadIdx.x;

  for (int task = tid; task < 2000; task += 256) {
    int chunk = task & 7;
    int rest = task >> 3;
    int xpair = rest % 25;
    int r = rest / 25;
    int y = band * 10 + r;
    const float* base = xg + (chunk * 8) * 2500 + y * 50 + xpair * 2;
    float2 v[8];
#pragma unroll
    for (int k = 0; k < 8; ++k) v[k] = *(const float2*)(base + k * 2500);
    uint4 a, b;
    a.x = (unsigned)bf16r(v[0].x) | ((unsigned)bf16r(v[1].x) << 16);
    a.y = (unsigned)bf16r(v[2].x) | ((unsigned)bf16r(v[3].x) << 16);
    a.z = (unsigned)bf16r(v[4].x) | ((unsigned)bf16r(v[5].x) << 16);
    a.w = (unsigned)bf16r(v[6].x) | ((unsigned)bf16r(v[7].x) << 16);
    b.x = (unsigned)bf16r(v[0].y) | ((unsigned)bf16r(v[1].y) << 16);
    b.y = (unsigned)bf16r(v[2].y) | ((unsigned)bf16r(v[3].y) << 16);
    b.z = (unsigned)bf16r(v[4].y) | ((unsigned)bf16r(v[5].y) << 16);
    b.w = (unsigned)bf16r(v[6].y) | ((unsigned)bf16r(v[7].y) << 16);
    int xx = xpair * 2;
    *(uint4*)&xsg[(((y + 1) * 52) + (xx + 1)) * 64 + chunk * 8] = a;
    *(uint4*)&xsg[(((y + 1) * 52) + (xx + 2)) * 64 + chunk * 8] = b;
  }
  uint4 z4;
  z4.x = 0; z4.y = 0; z4.z = 0; z4.w = 0;
  for (int task = tid; task < 160; task += 256) {
    int chunk = task & 7;
    int rest = task >> 3;
    int col = (rest & 1) ? 51 : 0;
    int r = rest >> 1;
    int y = band * 10 + r;
    *(uint4*)&xsg[(((y + 1) * 52) + col) * 64 + chunk * 8] = z4;
  }
  if (band == 0) {
    for (int task = tid; task < 416; task += 256)
      *(uint4*)&xsg[(task >> 3) * 64 + (task & 7) * 8] = z4;
  }
  if (band == 4) {
    for (int task = tid; task < 416; task += 256)
      *(uint4*)&xsg[(51 * 52 + (task >> 3)) * 64 + (task & 7) * 8] = z4;
  }

  for (int task = tid; task < 640; task += 256) {
    int r = task % 10;
    int c = task / 10;
    const float2* row = (const float2*)(xg + c * 2500 + (band * 10 + r) * 50);
#pragma unroll
    for (int ox = 0; ox < 5; ++ox) {
      float2 v0 = row[ox * 5 + 0], v1 = row[ox * 5 + 1], v2 = row[ox * 5 + 2];
      float2 v3 = row[ox * 5 + 3], v4 = row[ox * 5 + 4];
      float m = fmaxf(fmaxf(fmaxf(v0.x, v0.y), fmaxf(v1.x, v1.y)),
                      fmaxf(fmaxf(v2.x, v2.y), fmaxf(v3.x, v3.y)));
      m = fmaxf(m, fmaxf(v4.x, v4.y));
      pm[(c * 10 + r) * 5 + ox] = m;
    }
  }
  __syncthreads();
  for (int t2 = tid; t2 < 320; t2 += 256) {
    int ox = t2 % 5, c = t2 / 5;
    float m = pm[(c * 10) * 5 + ox];
#pragma unroll
    for (int r = 1; r < 10; ++r) m = fmaxf(m, pm[(c * 10 + r) * 5 + ox]);
    pooled[(size_t)g * 1600 + c * 25 + band * 5 + ox] = m;
  }
}

// ---- wscale: per-group scaled weights in MFMA A-fragment order -------------
__global__ __launch_bounds__(256) void wscale_kernel(
    const float* __restrict__ w, const float* __restrict__ scale_g,
    unsigned short* __restrict__ wt3) {
  const int g = blockIdx.x;
  const int tid = threadIdx.x;
  __shared__ float sc[64];
  if (tid < 64) sc[tid] = scale_g[g * 64 + tid];
  __syncthreads();
  unsigned short* outg = wt3 + (size_t)g * 36864;
  for (int idx = tid; idx < 36864; idx += 256) {
    int j = idx & 7;
    int lane = (idx >> 3) & 63;
    int mf = (idx >> 9) & 3;
    int ik = (idx >> 11) & 1;
    int tap = idx >> 12;
    int o = mf * 16 + (lane & 15);
    int i = ik * 32 + 8 * (lane >> 4) + j;
    outg[idx] = bf16r(w[((o * 64) + i) * 9 + tap] * sc[i]);
  }
}

// ---- conv_main_fast: DMA-staged MFMA conv --------------------------------
__global__ __launch_bounds__(256) void conv_main_fast(
    const unsigned short* __restrict__ xs, const unsigned short* __restrict__ wt3,
    const float* __restrict__ fb_g, float* __restrict__ out) {
  const int g = blockIdx.x & 127;
  const int band = blockIdx.x >> 7;
  const int y0 = band * 4;
  const int tid = threadIdx.x;
  __shared__ unsigned short in_s[6 * 66 * 64];
  __shared__ float fb_s[64];
  if (tid < 64) fb_s[tid] = fb_g[g * 64 + tid];

  const unsigned short* xsg = xs + (size_t)g * (52 * 52 * 64);
  for (int task = tid; task < 3168; task += 256) {
    int chunk = task & 7;
    int c = (task >> 3) % 66;
    int r = (task >> 3) / 66;
    int py = y0 + r;
    int srcChunk = chunk ^ (c & 7);
    const unsigned short* src = xsg + ((size_t)(py * 52 + c) * 64 + srcChunk * 8);
    unsigned short* ldsb = in_s + (size_t)(task & ~63) * 8;
    __builtin_amdgcn_global_load_lds(
        (const __attribute__((address_space(1))) void*)src,
        (__attribute__((address_space(3))) void*)ldsb, 16, 0, 0);
  }
  __syncthreads();

  const int wave = tid >> 6, lane = tid & 63;
  const int l15 = lane & 15, l4 = lane >> 4;
  const int yrow = y0 + wave;
  if (yrow < 50) {
    f32x4 acc[4][4];
    f32x4 z = {0.f, 0.f, 0.f, 0.f};
#pragma unroll
    for (int mf = 0; mf < 4; ++mf)
#pragma unroll
      for (int nf = 0; nf < 4; ++nf) acc[mf][nf] = z;

    const unsigned short* wg = wt3 + (size_t)g * 36864;
#pragma unroll
    for (int dy = 0; dy < 3; ++dy) {
      const int rr = wave + dy;
#pragma unroll
      for (int dx = 0; dx < 3; ++dx) {
        const int tap = dy * 3 + dx;
#pragma unroll
        for (int ik = 0; ik < 2; ++ik) {
          s16x8 a[4], bfr[4];
#pragma unroll
          for (int mf = 0; mf < 4; ++mf)
            a[mf] = *reinterpret_cast<const s16x8*>(
                wg + ((((tap * 2 + ik) * 4 + mf) * 64 + lane) << 3));
#pragma unroll
          for (int nf = 0; nf < 4; ++nf) {
            int cc = nf * 16 + l15 + dx;
            int chS = (ik * 4 + l4) ^ (cc & 7);
            bfr[nf] = *reinterpret_cast<const s16x8*>(
                &in_s[((rr * 66 + cc) << 6) + (chS << 3)]);
          }
#pragma unroll
          for (int mf = 0; mf < 4; ++mf)
#pragma unroll
            for (int nf = 0; nf < 4; ++nf)
              acc[mf][nf] = __builtin_amdgcn_mfma_f32_16x16x32_bf16(
                  a[mf], bfr[nf], acc[mf][nf], 0, 0, 0);
        }
      }
    }
    float* og = out + (size_t)g * 64 * 2500 + yrow * 50;
#pragma unroll
    for (int mf = 0; mf < 4; ++mf) {
#pragma unroll
      for (int r = 0; r < 4; ++r) {
        int o = mf * 16 + l4 * 4 + r;
        float fbv = fb_s[o];
#pragma unroll
        for (int nf = 0; nf < 4; ++nf) {
          int xx = nf * 16 + l15;
          if (xx < 50) og[(size_t)o * 2500 + xx] = acc[mf][nf][r] + fbv;
        }
      }
    }
  }
}

// ============================================================================
//                       LEGACY (round-1) PATH — fallback
// ============================================================================

__global__ __launch_bounds__(256) void pool_kernel(const float* __restrict__ x,
                                                   float* __restrict__ pooled) {
  const int blk = blockIdx.x;
  const float* plane = x + (size_t)blk * 2500;
  __shared__ float pmax[250];
  const int t = threadIdx.x;
  if (t < 250) {
    int r = t / 5, cc = t % 5;
    const float* row = plane + r * 50 + cc * 10;
    float m = row[0];
#pragma unroll
    for (int j = 1; j < 10; ++j) m = fmaxf(m, row[j]);
    pmax[r * 5 + cc] = m;
  }
  __syncthreads();
  if (t < 25) {
    int pr = t / 5, cc = t % 5;
    float m = pmax[(pr * 10) * 5 + cc];
#pragma unroll
    for (int rr = 1; rr < 10; ++rr) m = fmaxf(m, pmax[(pr * 10 + rr) * 5 + cc]);
    pooled[(size_t)blk * 25 + t] = m;
  }
}

__global__ __launch_bounds__(256) void wt_kernel(const float* __restrict__ w,
                                                 unsigned short* __restrict__ wt2) {
  int idx = blockIdx.x * 256 + threadIdx.x;
  if (idx >= 36864) return;
  int j = idx & 7;
  int lane = (idx >> 3) & 63;
  int mf = (idx >> 9) & 3;
  int ik = (idx >> 11) & 1;
  int tap = idx >> 12;
  int o = mf * 16 + (lane & 15);
  int i = ik * 32 + 8 * (lane >> 4) + j;
  wt2[idx] = bf16r(w[((o * 64) + i) * 9 + tap]);
}

__global__ __launch_bounds__(256) void conv_main(
    const float* __restrict__ x, const unsigned short* __restrict__ wt2,
    const float* __restrict__ scale_g, const float* __restrict__ fb_g,
    float* __restrict__ out) {
  const int g = blockIdx.x & 127;
  const int band = blockIdx.x >> 7;
  const int y0 = band * 4;
  const int tid = threadIdx.x;
  __shared__ unsigned short in_s[6 * 66 * 64];
  __shared__ float scale_s[64], fb_s[64];
  if (tid < 64) {
    scale_s[tid] = scale_g[g * 64 + tid];
    fb_s[tid] = fb_g[g * 64 + tid];
  }
  __syncthreads();
  const float* xg = x + (size_t)g * 160000;
  for (int task = tid; task < 3168; task += 256) {
    int c = task % 66;
    int rc = task / 66;
    int r = rc >> 3;
    int chunk = rc & 7;
    int y = y0 - 1 + r;
    int xi = c - 1;
    unsigned int p0 = 0, p1 = 0, p2 = 0, p3 = 0;
    if (y >= 0 && y < 50 && xi >= 0 && xi < 50) {
      const float* px = xg + chunk * 8 * 2500 + y * 50 + xi;
      float f0 = px[0] * scale_s[chunk * 8 + 0];
      float f1 = px[2500] * scale_s[chunk * 8 + 1];
      float f2 = px[5000] * scale_s[chunk * 8 + 2];
      float f3 = px[7500] * scale_s[chunk * 8 + 3];
      float f4 = px[10000] * scale_s[chunk * 8 + 4];
      float f5 = px[12500] * scale_s[chunk * 8 + 5];
      float f6 = px[15000] * scale_s[chunk * 8 + 6];
      float f7 = px[17500] * scale_s[chunk * 8 + 7];
      p0 = (unsigned)bf16r(f0) | ((unsigned)bf16r(f1) << 16);
      p1 = (unsigned)bf16r(f2) | ((unsigned)bf16r(f3) << 16);
      p2 = (unsigned)bf16r(f4) | ((unsigned)bf16r(f5) << 16);
      p3 = (unsigned)bf16r(f6) | ((unsigned)bf16r(f7) << 16);
    }
    int chS = chunk ^ (c & 7);
    uint4* dst = (uint4*)&in_s[((r * 66 + c) << 6) + (chS << 3)];
    uint4 u4;
    u4.x = p0; u4.y = p1; u4.z = p2; u4.w = p3;
    *dst = u4;
  }
  __syncthreads();
  const int wave = tid >> 6, lane = tid & 63;
  const int l15 = lane & 15, l4 = lane >> 4;
  const int yrow = y0 + wave;
  if (yrow < 50) {
    f32x4 acc[4][4];
    f32x4 z = {0.f, 0.f, 0.f, 0.f};
#pragma unroll
    for (int mf = 0; mf < 4; ++mf)
#pragma unroll
      for (int nf = 0; nf < 4; ++nf) acc[mf][nf] = z;
#pragma unroll
    for (int dy = 0; dy < 3; ++dy) {
      const int rr = wave + dy;
#pragma unroll
      for (int dx = 0; dx < 3; ++dx) {
        const int tap = dy * 3 + dx;
#pragma unroll
        for (int ik = 0; ik < 2; ++ik) {
          s16x8 a[4], bfr[4];
#pragma unroll
          for (int mf = 0; mf < 4; ++mf)
            a[mf] = *reinterpret_cast<const s16x8*>(
                wt2 + ((((tap * 2 + ik) * 4 + mf) * 64 + lane) << 3));
#pragma unroll
          for (int nf = 0; nf < 4; ++nf) {
            int cc = nf * 16 + l15 + dx;
            int chS = (ik * 4 + l4) ^ (cc & 7);
            bfr[nf] = *reinterpret_cast<const s16x8*>(
                &in_s[((rr * 66 + cc) << 6) + (chS << 3)]);
          }
#pragma unroll
          for (int mf = 0; mf < 4; ++mf)
#pragma unroll
            for (int nf = 0; nf < 4; ++nf)
              acc[mf][nf] = __builtin_amdgcn_mfma_f32_16x16x32_bf16(
                  a[mf], bfr[nf], acc[mf][nf], 0, 0, 0);
        }
      }
    }
    float* og = out + (size_t)g * 64 * 2500 + yrow * 50;
#pragma unroll
    for (int mf = 0; mf < 4; ++mf) {
#pragma unroll
      for (int r = 0; r < 4; ++r) {
        int o = mf * 16 + l4 * 4 + r;
        float fbv = fb_s[o];
#pragma unroll
        for (int nf = 0; nf < 4; ++nf) {
          int xx = nf * 16 + l15;
          if (xx < 50) og[(size_t)o * 2500 + xx] = acc[mf][nf][r] + fbv;
        }
      }
    }
  }
}

// ============================================================================
//                      convB (unchanged) + scan v2 + calib
// ============================================================================

__device__ __forceinline__ void conv64(const float* pool_s, const float* __restrict__ wgt,
                                       const float* __restrict__ bias, float* red,
                                       float* __restrict__ outg, int tid) {
  int co = tid & 63, qd = tid >> 6;
  float acc[25];
#pragma unroll
  for (int n = 0; n < 25; ++n) acc[n] = 0.f;
  for (int ci = qd * 16; ci < qd * 16 + 16; ++ci) {
    float in[25];
#pragma unroll
    for (int n = 0; n < 25; ++n) in[n] = pool_s[ci * 25 + n];
    float w9[9];
#pragma unroll
    for (int tp = 0; tp < 9; ++tp) w9[tp] = wgt[(co * 64 + ci) * 9 + tp];
#pragma unroll
    for (int n = 0; n < 25; ++n) {
      int y = n / 5, xx = n % 5;
#pragma unroll
      for (int dy = 0; dy < 3; ++dy) {
        int yy = y + dy - 1;
        if (yy < 0 || yy > 4) continue;
#pragma unroll
        for (int dx = 0; dx < 3; ++dx) {
          int xc = xx + dx - 1;
          if (xc < 0 || xc > 4) continue;
          acc[n] += in[yy * 5 + xc] * w9[dy * 3 + dx];
        }
      }
    }
  }
#pragma unroll
  for (int n = 0; n < 25; ++n) red[(qd * 64 + co) * 25 + n] = acc[n];
  __syncthreads();
  for (int idx = tid; idx < 1600; idx += 256) {
    float s = red[idx] + red[1600 + idx] + red[3200 + idx] + red[4800 + idx];
    outg[idx] = s + bias[idx / 25];
  }
  __syncthreads();
}

__device__ __forceinline__ void conv4(const float* pool_s, const float* __restrict__ wgt,
                                      const float* __restrict__ bias, float* red,
                                      float* __restrict__ outg, int tid) {
  int co = tid & 3, ci = tid >> 2;
  float acc[25];
#pragma unroll
  for (int n = 0; n < 25; ++n) acc[n] = 0.f;
  float in[25];
#pragma unroll
  for (int n = 0; n < 25; ++n) in[n] = pool_s[ci * 25 + n];
  float w9[9];
#pragma unroll
  for (int tp = 0; tp < 9; ++tp) w9[tp] = wgt[(co * 64 + ci) * 9 + tp];
#pragma unroll
  for (int n = 0; n < 25; ++n) {
    int y = n / 5, xx = n % 5;
#pragma unroll
    for (int dy = 0; dy < 3; ++dy) {
      int yy = y + dy - 1;
      if (yy < 0 || yy > 4) continue;
#pragma unroll
      for (int dx = 0; dx < 3; ++dx) {
        int xc = xx + dx - 1;
        if (xc < 0 || xc > 4) continue;
        acc[n] += in[yy * 5 + xc] * w9[dy * 3 + dx];
      }
    }
  }
#pragma unroll
  for (int n = 0; n < 25; ++n) red[(ci * 4 + co) * 25 + n] = acc[n];
  __syncthreads();
  if (tid < 100) {
    int co2 = tid / 25, n = tid % 25;
    float s = 0.f;
    for (int c = 0; c < 64; ++c) s += red[(c * 4 + co2) * 25 + n];
    outg[co2 * 25 + n] = s + bias[co2];
  }
  __syncthreads();
}

__global__ __launch_bounds__(256) void convB_kernel(
    const float* __restrict__ pooled, const float* __restrict__ vw,
    const float* __restrict__ vb, const float* __restrict__ kw,
    const float* __restrict__ kb, const float* __restrict__ iw,
    const float* __restrict__ ib, float* __restrict__ vconv,
    float* __restrict__ kconv, float* __restrict__ prior0) {
  const int blk = blockIdx.x;
  __shared__ float pool_s[1600];
  __shared__ float red[6400];
  const int tid = threadIdx.x;
  for (int idx = tid; idx < 1600; idx += 256) pool_s[idx] = pooled[blk * 1600 + idx];
  __syncthreads();
  conv64(pool_s, vw, vb, red, vconv + blk * 1600, tid);
  conv4(pool_s, kw, kb, red, kconv + blk * 100, tid);
  if ((blk & 7) == 0) conv64(pool_s, iw, ib, red, prior0 + (blk >> 3) * 1600, tid);
}

// ---- scan v2: 16 blocks (one per batch), 256 threads, 4 phases/step -------
// Writes avgg[b*8+l][64] (mean over 25 positions of each step's attention out)
__global__ __launch_bounds__(256) void scan2_kernel(
    const float* __restrict__ vconv, const float* __restrict__ kconv,
    const float* __restrict__ prior0, const float* __restrict__ qw,
    const float* __restrict__ qb, float* __restrict__ avgg) {
  const int b = blockIdx.x;
  const int tid = threadIdx.x;
  __shared__ float v_all[8 * 64 * 28];   // rows padded to 28, pads = 0
  __shared__ float kk_all[8 * 100];
  __shared__ float p_s[1600];
  __shared__ float q_s[100];
  __shared__ float qb_s[4];
  __shared__ float attn_s[25 * 28];      // rows padded to 28, pads = 0
  __shared__ float red[100 * 68];        // [(co*25+n)][ci], padded 68
  __shared__ float avgp[64 * 4];         // per-(c,grp) partial sums
  __shared__ float qw_s[2304];

  // ---- preload everything once ----
  for (int idx = tid; idx < 8 * 64 * 28; idx += 256) {
    int m = idx % 28;
    int rest = idx / 28;          // l*64 + c
    v_all[idx] = (m < 25) ? vconv[b * 12800 + rest * 25 + m] : 0.f;
  }
  for (int idx = tid; idx < 800; idx += 256) kk_all[idx] = kconv[b * 800 + idx];
  for (int idx = tid; idx < 1600; idx += 256) p_s[idx] = prior0[b * 1600 + idx];
  for (int idx = tid; idx < 2304; idx += 256) qw_s[idx] = qw[idx];
  if (tid < 4) qb_s[tid] = qb[tid];
  __syncthreads();

  const int qco = tid & 3, qci = tid >> 2;
  float qwr[9];
#pragma unroll
  for (int tp = 0; tp < 9; ++tp) qwr[tp] = qw_s[(qco * 64 + qci) * 9 + tp];

  for (int l = 0; l < 8; ++l) {
    // ---- Phase 1: q-conv partials (+ off-path avg store for step l-1) ----
    {
      float in[25];
#pragma unroll
      for (int n = 0; n < 25; ++n) in[n] = p_s[qci * 25 + n];
      float acc[25];
#pragma unroll
      for (int n = 0; n < 25; ++n) acc[n] = 0.f;
#pragma unroll
      for (int n = 0; n < 25; ++n) {
        int y = n / 5, xx = n % 5;
#pragma unroll
        for (int dy = 0; dy < 3; ++dy) {
          int yy = y + dy - 1;
          if (yy < 0 || yy > 4) continue;
#pragma unroll
          for (int dx = 0; dx < 3; ++dx) {
            int xc = xx + dx - 1;
            if (xc < 0 || xc > 4) continue;
            acc[n] += in[yy * 5 + xc] * qwr[dy * 3 + dx];
          }
        }
      }
#pragma unroll
      for (int n = 0; n < 25; ++n) red[(qco * 25 + n) * 68 + qci] = acc[n];
    }
    if (l > 0 && tid < 64) {
      float4 a4 = *(float4*)&avgp[tid * 4];
      avgg[(b * 8 + l - 1) * 64 + tid] = (a4.x + a4.y + a4.z + a4.w) * 0.04f;
    }
    __syncthreads();

    // ---- Phase 2: reduce 64 ci partials -> q_s (vectorized b128 reads) ----
    if (tid < 200) {
      int row = tid >> 1, h = tid & 1;  // row = co*25+n
      const float* rp = &red[row * 68 + h * 32];
      float s = 0.f;
#pragma unroll
      for (int j = 0; j < 8; ++j) {
        float4 r4 = *(const float4*)(rp + 4 * j);
        s += r4.x + r4.y + r4.z + r4.w;
      }
      s += __shfl_down(s, 1);
      if (h == 0) q_s[row] = s + qb_s[row / 25];
    }
    __syncthreads();

    // ---- Phase 3: qk + softmax fused, one row per thread, in registers ----
    if (tid < 25) {
      const int n = tid;
      const float* kk = &kk_all[l * 100];
      float q0 = q_s[n], q1 = q_s[25 + n], q2 = q_s[50 + n], q3 = q_s[75 + n];
      float row[25];
      float mx = -1e30f;
#pragma unroll
      for (int m = 0; m < 25; ++m) {
        float s = q0 * kk[m] + q1 * kk[25 + m] + q2 * kk[50 + m] + q3 * kk[75 + m];
        row[m] = s;
        mx = fmaxf(mx, s);
      }
      float sm = 0.f;
#pragma unroll
      for (int m = 0; m < 25; ++m) {
        float e = __expf(row[m] - mx);
        row[m] = e;
        sm += e;
      }
      float inv = 1.0f / sm;
#pragma unroll
      for (int m = 0; m < 25; ++m) attn_s[n * 28 + m] = row[m] * inv;
      attn_s[n * 28 + 25] = 0.f;
      attn_s[n * 28 + 26] = 0.f;
      attn_s[n * 28 + 27] = 0.f;
    }
    __syncthreads();

    // ---- Phase 4: pv (p_new = V attn^T) + per-thread avg partials --------
    {
      const int c = tid & 63, grp = tid >> 6;
      float4 v4[7];
      const float* vr = &v_all[(l * 64 + c) * 28];
#pragma unroll
      for (int j = 0; j < 7; ++j) v4[j] = *(const float4*)(vr + 4 * j);
      float partial = 0.f;
      for (int n = grp; n < 25; n += 4) {
        const float* ar = &attn_s[n * 28];
        float acc = 0.f;
#pragma unroll
        for (int j = 0; j < 7; ++j) {
          float4 a4 = *(const float4*)(ar + 4 * j);
          acc += v4[j].x * a4.x + v4[j].y * a4.y + v4[j].z * a4.z + v4[j].w * a4.w;
        }
        p_s[c * 25 + n] = acc;
        partial += acc;
      }
      avgp[c * 4 + grp] = partial;
    }
    __syncthreads();
  }
  // final step's avg
  if (tid < 64) {
    float4 a4 = *(float4*)&avgp[tid * 4];
    avgg[(b * 8 + 7) * 64 + tid] = (a4.x + a4.y + a4.z + a4.w) * 0.04f;
  }
}

// ---- calib: scale/fb from avgg, parallel over all 128 (b,l) ---------------
// grid: 32 blocks x 256 threads; wave = one bl row (o = lane)
__global__ __launch_bounds__(256) void calib_kernel(
    const float* __restrict__ avgg, const float* __restrict__ tconvw,
    const float* __restrict__ tconvb, const float* __restrict__ fcw,
    const float* __restrict__ fcb, const float* __restrict__ bias,
    float* __restrict__ scale_g, float* __restrict__ fb_g) {
  const int tid = threadIdx.x;
  const int wave = tid >> 6, o = tid & 63;
  const int bl = blockIdx.x * 4 + wave;
  __shared__ float tcw_s[64 * 65];
  __shared__ float avgl[4][64];
  for (int idx = tid; idx < 4096; idx += 256)
    tcw_s[(idx >> 6) * 65 + (idx & 63)] = tconvw[idx];
  avgl[wave][o] = avgg[bl * 64 + o];
  __syncthreads();

  float cal = tconvb[o];
  const float* av = avgl[wave];
#pragma unroll
  for (int c = 0; c < 64; ++c) cal += tcw_s[o * 65 + c] * av[c];
  scale_g[bl * 64 + o] = 1.0f + cal;

  float part = fcw[o] * av[o];
#pragma unroll
  for (int off = 32; off; off >>= 1) part += __shfl_down(part, off);
  float fc = __shfl(part, 0) + fcb[0];
  fb_g[bl * 64 + o] = bias[o] * (1.0f + fc);
}

// --------------------------------- launch ---------------------------------
extern "C" void kernel_launch(void* const* d_in, const int* in_sizes, int n_in,
                              void* d_out, int out_size, void* d_ws, size_t ws_size,
                              hipStream_t stream) {
  const float* x       = (const float*)d_in[0];
  const float* weight  = (const float*)d_in[1];
  const float* bias    = (const float*)d_in[2];
  const float* init_w  = (const float*)d_in[3];
  const float* init_b  = (const float*)d_in[4];
  const float* q_w     = (const float*)d_in[5];
  const float* q_b     = (const float*)d_in[6];
  const float* k_w     = (const float*)d_in[7];
  const float* k_b     = (const float*)d_in[8];
  const float* v_w     = (const float*)d_in[9];
  const float* v_b     = (const float*)d_in[10];
  const float* tconv_w = (const float*)d_in[11];
  const float* tconv_b = (const float*)d_in[12];
  const float* fc_w    = (const float*)d_in[13];
  const float* fc_b    = (const float*)d_in[14];
  float* out = (float*)d_out;

  float* ws = (float*)d_ws;
  float* pooled = ws;                  // 204800 f
  float* vconv  = ws + 204800;         // 204800 f
  float* kconv  = ws + 409600;         // 12800 f
  float* prior0 = ws + 422400;         // 25600 f
  float* scaleg = ws + 448000;         // 8192 f
  float* fbg    = ws + 456192;         // 8192 f
  float* avgg   = ws + 464384;         // 8192 f
  unsigned short* wt3 = (unsigned short*)(ws + 472576);   // 4718592 us
  unsigned short* xsb = wt3 + 4718592;                    // 22151168 us

  const size_t NEED_FAST = 55695360ull;  // floats + wt3 + xs + 64KB OOB slack

  if (ws_size >= NEED_FAST) {
    poolprep_kernel<<<640, 256, 0, stream>>>(x, pooled, xsb);
    convB_kernel<<<128, 256, 0, stream>>>(pooled, v_w, v_b, k_w, k_b, init_w, init_b,
                                          vconv, kconv, prior0);
    scan2_kernel<<<16, 256, 0, stream>>>(vconv, kconv, prior0, q_w, q_b, avgg);
    calib_kernel<<<32, 256, 0, stream>>>(avgg, tconv_w, tconv_b, fc_w, fc_b, bias,
                                         scaleg, fbg);
    wscale_kernel<<<128, 256, 0, stream>>>(weight, scaleg, wt3);
    conv_main_fast<<<13 * 128, 256, 0, stream>>>(xsb, wt3, fbg, out);
  } else {
    unsigned short* wt2 = (unsigned short*)(ws + 472576);
    pool_kernel<<<8192, 256, 0, stream>>>(x, pooled);
    wt_kernel<<<144, 256, 0, stream>>>(weight, wt2);
    convB_kernel<<<128, 256, 0, stream>>>(pooled, v_w, v_b, k_w, k_b, init_w, init_b,
                                          vconv, kconv, prior0);
    scan2_kernel<<<16, 256, 0, stream>>>(vconv, kconv, prior0, q_w, q_b, avgg);
    calib_kernel<<<32, 256, 0, stream>>>(avgg, tconv_w, tconv_b, fc_w, fc_b, bias,
                                         scaleg, fbg);
    conv_main<<<13 * 128, 256, 0, stream>>>(x, wt2, scaleg, fbg, out);
  }
}

// Round 5
// 162.971 us; speedup vs baseline: 1.1935x; 1.1448x over previous
//
#include <hip/hip_runtime.h>

typedef short s16x8 __attribute__((ext_vector_type(8)));
typedef float f32x4 __attribute__((ext_vector_type(4)));

__device__ __forceinline__ unsigned short bf16r(float f) {
  unsigned int u = __float_as_uint(f);
  u += 0x7fffu + ((u >> 16) & 1u);
  return (unsigned short)(u >> 16);
}

// ============================================================================
//                                FAST PATH
// ============================================================================

// ---- K1 v2: fused max-pool + x -> padded NHWC bf16, 2x parallelism --------
// grid: 128 g * 5 band * 2 chalf = 1280 blocks, 256 threads.
// Each block: 32 channels (chunks ch0..ch0+3) x 10 rows. Pool partials kept in
// LDS from phase-A registers (no global re-read).
__global__ __launch_bounds__(256) void poolprep2_kernel(
    const float* __restrict__ x, float* __restrict__ pooled,
    unsigned short* __restrict__ xs) {
  const int blk = blockIdx.x;
  const int g = blk / 10;
  const int rem = blk % 10;
  const int band = rem >> 1;        // rows y in [band*10, band*10+10)
  const int chalf = rem & 1;        // chunk half: chunks ch0..ch0+3
  const int ch0 = chalf * 4;
  const float* xg = x + (size_t)g * 160000;
  unsigned short* xsg = xs + (size_t)g * (52 * 52 * 64);
  __shared__ float pm2[32 * 250];   // [c_local][r][xpair]
  const int tid = threadIdx.x;

  // Phase A: transpose + bf16 + pool partials. tasks (r,xpair,chunk4)=10*25*4
  for (int task = tid; task < 1000; task += 256) {
    int chunk4 = task & 3;
    int rest = task >> 2;
    int xpair = rest % 25;
    int r = rest / 25;
    int y = band * 10 + r;
    int chunk = ch0 + chunk4;
    const float* base = xg + (chunk * 8) * 2500 + y * 50 + xpair * 2;
    float2 v[8];
#pragma unroll
    for (int k = 0; k < 8; ++k) v[k] = *(const float2*)(base + k * 2500);
#pragma unroll
    for (int k = 0; k < 8; ++k)
      pm2[(chunk4 * 8 + k) * 250 + r * 25 + xpair] = fmaxf(v[k].x, v[k].y);
    uint4 a, b;
    a.x = (unsigned)bf16r(v[0].x) | ((unsigned)bf16r(v[1].x) << 16);
    a.y = (unsigned)bf16r(v[2].x) | ((unsigned)bf16r(v[3].x) << 16);
    a.z = (unsigned)bf16r(v[4].x) | ((unsigned)bf16r(v[5].x) << 16);
    a.w = (unsigned)bf16r(v[6].x) | ((unsigned)bf16r(v[7].x) << 16);
    b.x = (unsigned)bf16r(v[0].y) | ((unsigned)bf16r(v[1].y) << 16);
    b.y = (unsigned)bf16r(v[2].y) | ((unsigned)bf16r(v[3].y) << 16);
    b.z = (unsigned)bf16r(v[4].y) | ((unsigned)bf16r(v[5].y) << 16);
    b.w = (unsigned)bf16r(v[6].y) | ((unsigned)bf16r(v[7].y) << 16);
    int xx = xpair * 2;
    *(uint4*)&xsg[(((y + 1) * 52) + (xx + 1)) * 64 + chunk * 8] = a;
    *(uint4*)&xsg[(((y + 1) * 52) + (xx + 2)) * 64 + chunk * 8] = b;
  }
  // Border zeros (this block's 32 channels only)
  uint4 z4;
  z4.x = 0; z4.y = 0; z4.z = 0; z4.w = 0;
  for (int task = tid; task < 80; task += 256) {  // cols 0 and 51, 10 rows
    int chunk4 = task & 3;
    int rest = task >> 2;
    int col = (rest & 1) ? 51 : 0;
    int r = rest >> 1;
    int y = band * 10 + r;
    *(uint4*)&xsg[(((y + 1) * 52) + col) * 64 + (ch0 + chunk4) * 8] = z4;
  }
  if (band == 0) {  // padded row 0: 52 cols * 4 chunks = 208 tasks
    for (int task = tid; task < 208; task += 256)
      *(uint4*)&xsg[(task >> 2) * 64 + (ch0 + (task & 3)) * 8] = z4;
  }
  if (band == 4) {  // padded row 51
    for (int task = tid; task < 208; task += 256)
      *(uint4*)&xsg[(51 * 52 + (task >> 2)) * 64 + (ch0 + (task & 3)) * 8] = z4;
  }
  __syncthreads();
  // Phase B: LDS-only pool reduce. tasks (c_local, ox) = 160
  if (tid < 160) {
    int c_local = tid / 5, ox = tid % 5;
    const float* pr = &pm2[c_local * 250 + ox * 5];
    float m = -1e30f;
#pragma unroll
    for (int r = 0; r < 10; ++r) {
#pragma unroll
      for (int xp = 0; xp < 5; ++xp) m = fmaxf(m, pr[r * 25 + xp]);
    }
    int c_g = chalf * 32 + c_local;
    pooled[(size_t)g * 1600 + c_g * 25 + band * 5 + ox] = m;
  }
}

// ---- conv helper: one ik-half compute pass --------------------------------
__device__ __forceinline__ void conv_pass(
    const unsigned short* in_s, const unsigned short* __restrict__ wg,
    f32x4 acc[4][4], int ikk, int wave, int lane, int l15, int l4) {
#pragma unroll
  for (int dy = 0; dy < 3; ++dy) {
    const int rr = wave + dy;
#pragma unroll
    for (int dx = 0; dx < 3; ++dx) {
      const int tap = dy * 3 + dx;
      s16x8 a[4], bfr[4];
#pragma unroll
      for (int mf = 0; mf < 4; ++mf)
        a[mf] = *reinterpret_cast<const s16x8*>(
            wg + ((((tap * 2 + ikk) * 4 + mf) * 64 + lane) << 3));
#pragma unroll
      for (int nf = 0; nf < 4; ++nf) {
        int cc = nf * 16 + l15 + dx;
        int slot = l4 ^ ((cc ^ (cc >> 2)) & 3);
        bfr[nf] = *reinterpret_cast<const s16x8*>(
            &in_s[((rr * 66 + cc) << 5) + (slot << 3)]);
      }
#pragma unroll
      for (int mf = 0; mf < 4; ++mf)
#pragma unroll
        for (int nf = 0; nf < 4; ++nf)
          acc[mf][nf] = __builtin_amdgcn_mfma_f32_16x16x32_bf16(
              a[mf], bfr[nf], acc[mf][nf], 0, 0, 0);
    }
  }
}

// ---- conv_main v3: ik-split DMA staging, 24.75 KB LDS, 4 blocks/CU target -
__global__ __launch_bounds__(256, 4) void conv_main_fast2(
    const unsigned short* __restrict__ xs, const unsigned short* __restrict__ wt3,
    const float* __restrict__ fb_g, float* __restrict__ out) {
  const int g = blockIdx.x & 127;    // 13 bands of one g land on the same XCD
  const int band = blockIdx.x >> 7;  // 0..12
  const int y0 = band * 4;
  const int tid = threadIdx.x;
  __shared__ __align__(16) unsigned short in_s[6 * 66 * 32];
  __shared__ float fb_s[64];
  if (tid < 64) fb_s[tid] = fb_g[g * 64 + tid];

  const unsigned short* xsg = xs + (size_t)g * (52 * 52 * 64);
  const unsigned short* wg = wt3 + (size_t)g * 36864;
  const int wave = tid >> 6, lane = tid & 63;
  const int l15 = lane & 15, l4 = lane >> 4;
  const int yrow = y0 + wave;

  f32x4 acc[4][4];
  f32x4 z = {0.f, 0.f, 0.f, 0.f};
#pragma unroll
  for (int mf = 0; mf < 4; ++mf)
#pragma unroll
    for (int nf = 0; nf < 4; ++nf) acc[mf][nf] = z;

  // ---- stage ik=0 ----
  for (int task = tid; task < 1584; task += 256) {
    int slot = task & 3;
    int c = (task >> 2) % 66;
    int r = (task >> 2) / 66;
    int py = y0 + r;
    int srcSub = slot ^ ((c ^ (c >> 2)) & 3);
    const unsigned short* src = xsg + ((size_t)(py * 52 + c) * 64 + srcSub * 8);
    unsigned short* ldsb = in_s + (size_t)(task & ~63) * 8;
    __builtin_amdgcn_global_load_lds(
        (const __attribute__((address_space(1))) void*)src,
        (__attribute__((address_space(3))) void*)ldsb, 16, 0, 0);
  }
  __syncthreads();
  if (yrow < 50) conv_pass(in_s, wg, acc, 0, wave, lane, l15, l4);
  __syncthreads();
  // ---- stage ik=1 ----
  for (int task = tid; task < 1584; task += 256) {
    int slot = task & 3;
    int c = (task >> 2) % 66;
    int r = (task >> 2) / 66;
    int py = y0 + r;
    int srcSub = slot ^ ((c ^ (c >> 2)) & 3);
    const unsigned short* src = xsg + ((size_t)(py * 52 + c) * 64 + 32 + srcSub * 8);
    unsigned short* ldsb = in_s + (size_t)(task & ~63) * 8;
    __builtin_amdgcn_global_load_lds(
        (const __attribute__((address_space(1))) void*)src,
        (__attribute__((address_space(3))) void*)ldsb, 16, 0, 0);
  }
  __syncthreads();
  if (yrow < 50) {
    conv_pass(in_s, wg, acc, 1, wave, lane, l15, l4);
    float* og = out + (size_t)g * 64 * 2500 + yrow * 50;
#pragma unroll
    for (int mf = 0; mf < 4; ++mf) {
#pragma unroll
      for (int r = 0; r < 4; ++r) {
        int o = mf * 16 + l4 * 4 + r;
        float fbv = fb_s[o];
#pragma unroll
        for (int nf = 0; nf < 4; ++nf) {
          int xx = nf * 16 + l15;
          if (xx < 50) og[(size_t)o * 2500 + xx] = acc[mf][nf][r] + fbv;
        }
      }
    }
  }
}

// ---- calwt: fused calibration (scale/fb) + per-group scaled weight pack ---
// grid: 128 blocks (g = bl), 256 threads
__global__ __launch_bounds__(256) void calwt_kernel(
    const float* __restrict__ avgg, const float* __restrict__ tconvw,
    const float* __restrict__ tconvb, const float* __restrict__ fcw,
    const float* __restrict__ fcb, const float* __restrict__ bias,
    const float* __restrict__ w, float* __restrict__ fb_g,
    unsigned short* __restrict__ wt3) {
  const int g = blockIdx.x;
  const int tid = threadIdx.x;
  __shared__ float tcw_s[64 * 65];
  __shared__ float av[64];
  __shared__ float sc[64];
  for (int idx = tid; idx < 4096; idx += 256)
    tcw_s[(idx >> 6) * 65 + (idx & 63)] = tconvw[idx];
  if (tid < 64) av[tid] = avgg[g * 64 + tid];
  __syncthreads();
  if (tid < 64) {
    int o = tid;
    float cal = tconvb[o];
#pragma unroll
    for (int c = 0; c < 64; ++c) cal += tcw_s[o * 65 + c] * av[c];
    sc[o] = 1.0f + cal;
    float part = fcw[o] * av[o];
#pragma unroll
    for (int off = 32; off; off >>= 1) part += __shfl_down(part, off);
    float fc = __shfl(part, 0) + fcb[0];
    fb_g[g * 64 + o] = bias[o] * (1.0f + fc);
  }
  __syncthreads();
  unsigned short* outg = wt3 + (size_t)g * 36864;
  for (int idx = tid; idx < 36864; idx += 256) {
    int j = idx & 7;
    int lane = (idx >> 3) & 63;
    int mf = (idx >> 9) & 3;
    int ik = (idx >> 11) & 1;
    int tap = idx >> 12;
    int o = mf * 16 + (lane & 15);
    int i = ik * 32 + 8 * (lane >> 4) + j;
    outg[idx] = bf16r(w[((o * 64) + i) * 9 + tap] * sc[i]);
  }
}

// ============================================================================
//                       LEGACY PATH — fallback only
// ============================================================================

__global__ __launch_bounds__(256) void pool_kernel(const float* __restrict__ x,
                                                   float* __restrict__ pooled) {
  const int blk = blockIdx.x;
  const float* plane = x + (size_t)blk * 2500;
  __shared__ float pmax[250];
  const int t = threadIdx.x;
  if (t < 250) {
    int r = t / 5, cc = t % 5;
    const float* row = plane + r * 50 + cc * 10;
    float m = row[0];
#pragma unroll
    for (int j = 1; j < 10; ++j) m = fmaxf(m, row[j]);
    pmax[r * 5 + cc] = m;
  }
  __syncthreads();
  if (t < 25) {
    int pr = t / 5, cc = t % 5;
    float m = pmax[(pr * 10) * 5 + cc];
#pragma unroll
    for (int rr = 1; rr < 10; ++rr) m = fmaxf(m, pmax[(pr * 10 + rr) * 5 + cc]);
    pooled[(size_t)blk * 25 + t] = m;
  }
}

__global__ __launch_bounds__(256) void wt_kernel(const float* __restrict__ w,
                                                 unsigned short* __restrict__ wt2) {
  int idx = blockIdx.x * 256 + threadIdx.x;
  if (idx >= 36864) return;
  int j = idx & 7;
  int lane = (idx >> 3) & 63;
  int mf = (idx >> 9) & 3;
  int ik = (idx >> 11) & 1;
  int tap = idx >> 12;
  int o = mf * 16 + (lane & 15);
  int i = ik * 32 + 8 * (lane >> 4) + j;
  wt2[idx] = bf16r(w[((o * 64) + i) * 9 + tap]);
}

__global__ __launch_bounds__(256) void conv_main(
    const float* __restrict__ x, const unsigned short* __restrict__ wt2,
    const float* __restrict__ scale_g, const float* __restrict__ fb_g,
    float* __restrict__ out) {
  const int g = blockIdx.x & 127;
  const int band = blockIdx.x >> 7;
  const int y0 = band * 4;
  const int tid = threadIdx.x;
  __shared__ unsigned short in_s[6 * 66 * 64];
  __shared__ float scale_s[64], fb_s[64];
  if (tid < 64) {
    scale_s[tid] = scale_g[g * 64 + tid];
    fb_s[tid] = fb_g[g * 64 + tid];
  }
  __syncthreads();
  const float* xg = x + (size_t)g * 160000;
  for (int task = tid; task < 3168; task += 256) {
    int c = task % 66;
    int rc = task / 66;
    int r = rc >> 3;
    int chunk = rc & 7;
    int y = y0 - 1 + r;
    int xi = c - 1;
    unsigned int p0 = 0, p1 = 0, p2 = 0, p3 = 0;
    if (y >= 0 && y < 50 && xi >= 0 && xi < 50) {
      const float* px = xg + chunk * 8 * 2500 + y * 50 + xi;
      float f0 = px[0] * scale_s[chunk * 8 + 0];
      float f1 = px[2500] * scale_s[chunk * 8 + 1];
      float f2 = px[5000] * scale_s[chunk * 8 + 2];
      float f3 = px[7500] * scale_s[chunk * 8 + 3];
      float f4 = px[10000] * scale_s[chunk * 8 + 4];
      float f5 = px[12500] * scale_s[chunk * 8 + 5];
      float f6 = px[15000] * scale_s[chunk * 8 + 6];
      float f7 = px[17500] * scale_s[chunk * 8 + 7];
      p0 = (unsigned)bf16r(f0) | ((unsigned)bf16r(f1) << 16);
      p1 = (unsigned)bf16r(f2) | ((unsigned)bf16r(f3) << 16);
      p2 = (unsigned)bf16r(f4) | ((unsigned)bf16r(f5) << 16);
      p3 = (unsigned)bf16r(f6) | ((unsigned)bf16r(f7) << 16);
    }
    int chS = chunk ^ (c & 7);
    uint4* dst = (uint4*)&in_s[((r * 66 + c) << 6) + (chS << 3)];
    uint4 u4;
    u4.x = p0; u4.y = p1; u4.z = p2; u4.w = p3;
    *dst = u4;
  }
  __syncthreads();
  const int wave = tid >> 6, lane = tid & 63;
  const int l15 = lane & 15, l4 = lane >> 4;
  const int yrow = y0 + wave;
  if (yrow < 50) {
    f32x4 acc[4][4];
    f32x4 z = {0.f, 0.f, 0.f, 0.f};
#pragma unroll
    for (int mf = 0; mf < 4; ++mf)
#pragma unroll
      for (int nf = 0; nf < 4; ++nf) acc[mf][nf] = z;
#pragma unroll
    for (int dy = 0; dy < 3; ++dy) {
      const int rr = wave + dy;
#pragma unroll
      for (int dx = 0; dx < 3; ++dx) {
        const int tap = dy * 3 + dx;
#pragma unroll
        for (int ik = 0; ik < 2; ++ik) {
          s16x8 a[4], bfr[4];
#pragma unroll
          for (int mf = 0; mf < 4; ++mf)
            a[mf] = *reinterpret_cast<const s16x8*>(
                wt2 + ((((tap * 2 + ik) * 4 + mf) * 64 + lane) << 3));
#pragma unroll
          for (int nf = 0; nf < 4; ++nf) {
            int cc = nf * 16 + l15 + dx;
            int chS = (ik * 4 + l4) ^ (cc & 7);
            bfr[nf] = *reinterpret_cast<const s16x8*>(
                &in_s[((rr * 66 + cc) << 6) + (chS << 3)]);
          }
#pragma unroll
          for (int mf = 0; mf < 4; ++mf)
#pragma unroll
            for (int nf = 0; nf < 4; ++nf)
              acc[mf][nf] = __builtin_amdgcn_mfma_f32_16x16x32_bf16(
                  a[mf], bfr[nf], acc[mf][nf], 0, 0, 0);
        }
      }
    }
    float* og = out + (size_t)g * 64 * 2500 + yrow * 50;
#pragma unroll
    for (int mf = 0; mf < 4; ++mf) {
#pragma unroll
      for (int r = 0; r < 4; ++r) {
        int o = mf * 16 + l4 * 4 + r;
        float fbv = fb_s[o];
#pragma unroll
        for (int nf = 0; nf < 4; ++nf) {
          int xx = nf * 16 + l15;
          if (xx < 50) og[(size_t)o * 2500 + xx] = acc[mf][nf][r] + fbv;
        }
      }
    }
  }
}

__global__ __launch_bounds__(256) void calib_kernel(
    const float* __restrict__ avgg, const float* __restrict__ tconvw,
    const float* __restrict__ tconvb, const float* __restrict__ fcw,
    const float* __restrict__ fcb, const float* __restrict__ bias,
    float* __restrict__ scale_g, float* __restrict__ fb_g) {
  const int tid = threadIdx.x;
  const int wave = tid >> 6, o = tid & 63;
  const int bl = blockIdx.x * 4 + wave;
  __shared__ float tcw_s[64 * 65];
  __shared__ float avgl[4][64];
  for (int idx = tid; idx < 4096; idx += 256)
    tcw_s[(idx >> 6) * 65 + (idx & 63)] = tconvw[idx];
  avgl[wave][o] = avgg[bl * 64 + o];
  __syncthreads();
  float cal = tconvb[o];
  const float* av = avgl[wave];
#pragma unroll
  for (int c = 0; c < 64; ++c) cal += tcw_s[o * 65 + c] * av[c];
  scale_g[bl * 64 + o] = 1.0f + cal;
  float part = fcw[o] * av[o];
#pragma unroll
  for (int off = 32; off; off >>= 1) part += __shfl_down(part, off);
  float fc = __shfl(part, 0) + fcb[0];
  fb_g[bl * 64 + o] = bias[o] * (1.0f + fc);
}

// ============================================================================
//                      convB + scan2 (unchanged)
// ============================================================================

__device__ __forceinline__ void conv64(const float* pool_s, const float* __restrict__ wgt,
                                       const float* __restrict__ bias, float* red,
                                       float* __restrict__ outg, int tid) {
  int co = tid & 63, qd = tid >> 6;
  float acc[25];
#pragma unroll
  for (int n = 0; n < 25; ++n) acc[n] = 0.f;
  for (int ci = qd * 16; ci < qd * 16 + 16; ++ci) {
    float in[25];
#pragma unroll
    for (int n = 0; n < 25; ++n) in[n] = pool_s[ci * 25 + n];
    float w9[9];
#pragma unroll
    for (int tp = 0; tp < 9; ++tp) w9[tp] = wgt[(co * 64 + ci) * 9 + tp];
#pragma unroll
    for (int n = 0; n < 25; ++n) {
      int y = n / 5, xx = n % 5;
#pragma unroll
      for (int dy = 0; dy < 3; ++dy) {
        int yy = y + dy - 1;
        if (yy < 0 || yy > 4) continue;
#pragma unroll
        for (int dx = 0; dx < 3; ++dx) {
          int xc = xx + dx - 1;
          if (xc < 0 || xc > 4) continue;
          acc[n] += in[yy * 5 + xc] * w9[dy * 3 + dx];
        }
      }
    }
  }
#pragma unroll
  for (int n = 0; n < 25; ++n) red[(qd * 64 + co) * 25 + n] = acc[n];
  __syncthreads();
  for (int idx = tid; idx < 1600; idx += 256) {
    float s = red[idx] + red[1600 + idx] + red[3200 + idx] + red[4800 + idx];
    outg[idx] = s + bias[idx / 25];
  }
  __syncthreads();
}

__device__ __forceinline__ void conv4(const float* pool_s, const float* __restrict__ wgt,
                                      const float* __restrict__ bias, float* red,
                                      float* __restrict__ outg, int tid) {
  int co = tid & 3, ci = tid >> 2;
  float acc[25];
#pragma unroll
  for (int n = 0; n < 25; ++n) acc[n] = 0.f;
  float in[25];
#pragma unroll
  for (int n = 0; n < 25; ++n) in[n] = pool_s[ci * 25 + n];
  float w9[9];
#pragma unroll
  for (int tp = 0; tp < 9; ++tp) w9[tp] = wgt[(co * 64 + ci) * 9 + tp];
#pragma unroll
  for (int n = 0; n < 25; ++n) {
    int y = n / 5, xx = n % 5;
#pragma unroll
    for (int dy = 0; dy < 3; ++dy) {
      int yy = y + dy - 1;
      if (yy < 0 || yy > 4) continue;
#pragma unroll
      for (int dx = 0; dx < 3; ++dx) {
        int xc = xx + dx - 1;
        if (xc < 0 || xc > 4) continue;
        acc[n] += in[yy * 5 + xc] * w9[dy * 3 + dx];
      }
    }
  }
#pragma unroll
  for (int n = 0; n < 25; ++n) red[(ci * 4 + co) * 25 + n] = acc[n];
  __syncthreads();
  if (tid < 100) {
    int co2 = tid / 25, n = tid % 25;
    float s = 0.f;
    for (int c = 0; c < 64; ++c) s += red[(c * 4 + co2) * 25 + n];
    outg[co2 * 25 + n] = s + bias[co2];
  }
  __syncthreads();
}

__global__ __launch_bounds__(256) void convB_kernel(
    const float* __restrict__ pooled, const float* __restrict__ vw,
    const float* __restrict__ vb, const float* __restrict__ kw,
    const float* __restrict__ kb, const float* __restrict__ iw,
    const float* __restrict__ ib, float* __restrict__ vconv,
    float* __restrict__ kconv, float* __restrict__ prior0) {
  const int blk = blockIdx.x;
  __shared__ float pool_s[1600];
  __shared__ float red[6400];
  const int tid = threadIdx.x;
  for (int idx = tid; idx < 1600; idx += 256) pool_s[idx] = pooled[blk * 1600 + idx];
  __syncthreads();
  conv64(pool_s, vw, vb, red, vconv + blk * 1600, tid);
  conv4(pool_s, kw, kb, red, kconv + blk * 100, tid);
  if ((blk & 7) == 0) conv64(pool_s, iw, ib, red, prior0 + (blk >> 3) * 1600, tid);
}

__global__ __launch_bounds__(256) void scan2_kernel(
    const float* __restrict__ vconv, const float* __restrict__ kconv,
    const float* __restrict__ prior0, const float* __restrict__ qw,
    const float* __restrict__ qb, float* __restrict__ avgg) {
  const int b = blockIdx.x;
  const int tid = threadIdx.x;
  __shared__ float v_all[8 * 64 * 28];
  __shared__ float kk_all[8 * 100];
  __shared__ float p_s[1600];
  __shared__ float q_s[100];
  __shared__ float qb_s[4];
  __shared__ float attn_s[25 * 28];
  __shared__ float red[100 * 68];
  __shared__ float avgp[64 * 4];
  __shared__ float qw_s[2304];

  for (int idx = tid; idx < 8 * 64 * 28; idx += 256) {
    int m = idx % 28;
    int rest = idx / 28;
    v_all[idx] = (m < 25) ? vconv[b * 12800 + rest * 25 + m] : 0.f;
  }
  for (int idx = tid; idx < 800; idx += 256) kk_all[idx] = kconv[b * 800 + idx];
  for (int idx = tid; idx < 1600; idx += 256) p_s[idx] = prior0[b * 1600 + idx];
  for (int idx = tid; idx < 2304; idx += 256) qw_s[idx] = qw[idx];
  if (tid < 4) qb_s[tid] = qb[tid];
  __syncthreads();

  const int qco = tid & 3, qci = tid >> 2;
  float qwr[9];
#pragma unroll
  for (int tp = 0; tp < 9; ++tp) qwr[tp] = qw_s[(qco * 64 + qci) * 9 + tp];

  for (int l = 0; l < 8; ++l) {
    {
      float in[25];
#pragma unroll
      for (int n = 0; n < 25; ++n) in[n] = p_s[qci * 25 + n];
      float acc[25];
#pragma unroll
      for (int n = 0; n < 25; ++n) acc[n] = 0.f;
#pragma unroll
      for (int n = 0; n < 25; ++n) {
        int y = n / 5, xx = n % 5;
#pragma unroll
        for (int dy = 0; dy < 3; ++dy) {
          int yy = y + dy - 1;
          if (yy < 0 || yy > 4) continue;
#pragma unroll
          for (int dx = 0; dx < 3; ++dx) {
            int xc = xx + dx - 1;
            if (xc < 0 || xc > 4) continue;
            acc[n] += in[yy * 5 + xc] * qwr[dy * 3 + dx];
          }
        }
      }
#pragma unroll
      for (int n = 0; n < 25; ++n) red[(qco * 25 + n) * 68 + qci] = acc[n];
    }
    if (l > 0 && tid < 64) {
      float4 a4 = *(float4*)&avgp[tid * 4];
      avgg[(b * 8 + l - 1) * 64 + tid] = (a4.x + a4.y + a4.z + a4.w) * 0.04f;
    }
    __syncthreads();

    if (tid < 200) {
      int row = tid >> 1, h = tid & 1;
      const float* rp = &red[row * 68 + h * 32];
      float s = 0.f;
#pragma unroll
      for (int j = 0; j < 8; ++j) {
        float4 r4 = *(const float4*)(rp + 4 * j);
        s += r4.x + r4.y + r4.z + r4.w;
      }
      s += __shfl_down(s, 1);
      if (h == 0) q_s[row] = s + qb_s[row / 25];
    }
    __syncthreads();

    if (tid < 25) {
      const int n = tid;
      const float* kk = &kk_all[l * 100];
      float q0 = q_s[n], q1 = q_s[25 + n], q2 = q_s[50 + n], q3 = q_s[75 + n];
      float row[25];
      float mx = -1e30f;
#pragma unroll
      for (int m = 0; m < 25; ++m) {
        float s = q0 * kk[m] + q1 * kk[25 + m] + q2 * kk[50 + m] + q3 * kk[75 + m];
        row[m] = s;
        mx = fmaxf(mx, s);
      }
      float sm = 0.f;
#pragma unroll
      for (int m = 0; m < 25; ++m) {
        float e = __expf(row[m] - mx);
        row[m] = e;
        sm += e;
      }
      float inv = 1.0f / sm;
#pragma unroll
      for (int m = 0; m < 25; ++m) attn_s[n * 28 + m] = row[m] * inv;
      attn_s[n * 28 + 25] = 0.f;
      attn_s[n * 28 + 26] = 0.f;
      attn_s[n * 28 + 27] = 0.f;
    }
    __syncthreads();

    {
      const int c = tid & 63, grp = tid >> 6;
      float4 v4[7];
      const float* vr = &v_all[(l * 64 + c) * 28];
#pragma unroll
      for (int j = 0; j < 7; ++j) v4[j] = *(const float4*)(vr + 4 * j);
      float partial = 0.f;
      for (int n = grp; n < 25; n += 4) {
        const float* ar = &attn_s[n * 28];
        float acc = 0.f;
#pragma unroll
        for (int j = 0; j < 7; ++j) {
          float4 a4 = *(const float4*)(ar + 4 * j);
          acc += v4[j].x * a4.x + v4[j].y * a4.y + v4[j].z * a4.z + v4[j].w * a4.w;
        }
        p_s[c * 25 + n] = acc;
        partial += acc;
      }
      avgp[c * 4 + grp] = partial;
    }
    __syncthreads();
  }
  if (tid < 64) {
    float4 a4 = *(float4*)&avgp[tid * 4];
    avgg[(b * 8 + 7) * 64 + tid] = (a4.x + a4.y + a4.z + a4.w) * 0.04f;
  }
}

// --------------------------------- launch ---------------------------------
extern "C" void kernel_launch(void* const* d_in, const int* in_sizes, int n_in,
                              void* d_out, int out_size, void* d_ws, size_t ws_size,
                              hipStream_t stream) {
  const float* x       = (const float*)d_in[0];
  const float* weight  = (const float*)d_in[1];
  const float* bias    = (const float*)d_in[2];
  const float* init_w  = (const float*)d_in[3];
  const float* init_b  = (const float*)d_in[4];
  const float* q_w     = (const float*)d_in[5];
  const float* q_b     = (const float*)d_in[6];
  const float* k_w     = (const float*)d_in[7];
  const float* k_b     = (const float*)d_in[8];
  const float* v_w     = (const float*)d_in[9];
  const float* v_b     = (const float*)d_in[10];
  const float* tconv_w = (const float*)d_in[11];
  const float* tconv_b = (const float*)d_in[12];
  const float* fc_w    = (const float*)d_in[13];
  const float* fc_b    = (const float*)d_in[14];
  float* out = (float*)d_out;

  float* ws = (float*)d_ws;
  float* pooled = ws;                  // 204800 f
  float* vconv  = ws + 204800;         // 204800 f
  float* kconv  = ws + 409600;         // 12800 f
  float* prior0 = ws + 422400;         // 25600 f
  float* scaleg = ws + 448000;         // 8192 f (fallback only)
  float* fbg    = ws + 456192;         // 8192 f
  float* avgg   = ws + 464384;         // 8192 f
  unsigned short* wt3 = (unsigned short*)(ws + 472576);   // 4718592 us
  unsigned short* xsb = wt3 + 4718592;                    // 22151168 us

  const size_t NEED_FAST = 55695360ull;

  if (ws_size >= NEED_FAST) {
    poolprep2_kernel<<<1280, 256, 0, stream>>>(x, pooled, xsb);
    convB_kernel<<<128, 256, 0, stream>>>(pooled, v_w, v_b, k_w, k_b, init_w, init_b,
                                          vconv, kconv, prior0);
    scan2_kernel<<<16, 256, 0, stream>>>(vconv, kconv, prior0, q_w, q_b, avgg);
    calwt_kernel<<<128, 256, 0, stream>>>(avgg, tconv_w, tconv_b, fc_w, fc_b, bias,
                                          weight, fbg, wt3);
    conv_main_fast2<<<13 * 128, 256, 0, stream>>>(xsb, wt3, fbg, out);
  } else {
    unsigned short* wt2 = (unsigned short*)(ws + 472576);
    pool_kernel<<<8192, 256, 0, stream>>>(x, pooled);
    wt_kernel<<<144, 256, 0, stream>>>(weight, wt2);
    convB_kernel<<<128, 256, 0, stream>>>(pooled, v_w, v_b, k_w, k_b, init_w, init_b,
                                          vconv, kconv, prior0);
    scan2_kernel<<<16, 256, 0, stream>>>(vconv, kconv, prior0, q_w, q_b, avgg);
    calib_kernel<<<32, 256, 0, stream>>>(avgg, tconv_w, tconv_b, fc_w, fc_b, bias,
                                         scaleg, fbg);
    conv_main<<<13 * 128, 256, 0, stream>>>(x, wt2, scaleg, fbg, out);
  }
}

// Round 6
// 149.673 us; speedup vs baseline: 1.2996x; 1.0888x over previous
//
#include <hip/hip_runtime.h>

typedef short s16x8 __attribute__((ext_vector_type(8)));
typedef float f32x4 __attribute__((ext_vector_type(4)));
typedef unsigned int u32x4 __attribute__((ext_vector_type(4)));

__device__ __forceinline__ unsigned short bf16r(float f) {
  unsigned int u = __float_as_uint(f);
  u += 0x7fffu + ((u >> 16) & 1u);
  return (unsigned short)(u >> 16);
}
__device__ __forceinline__ float bf_lo(unsigned int u) {
  return __uint_as_float(u << 16);
}
__device__ __forceinline__ float bf_hi(unsigned int u) {
  return __uint_as_float(u & 0xffff0000u);
}

// ============================================================================
//                                FAST PATH
// ============================================================================

// ---- K1 v2: fused max-pool + x -> padded NHWC bf16 ------------------------
__global__ __launch_bounds__(256) void poolprep2_kernel(
    const float* __restrict__ x, float* __restrict__ pooled,
    unsigned short* __restrict__ xs) {
  const int blk = blockIdx.x;
  const int g = blk / 10;
  const int rem = blk % 10;
  const int band = rem >> 1;
  const int chalf = rem & 1;
  const int ch0 = chalf * 4;
  const float* xg = x + (size_t)g * 160000;
  unsigned short* xsg = xs + (size_t)g * (52 * 52 * 64);
  __shared__ float pm2[32 * 250];
  const int tid = threadIdx.x;

  for (int task = tid; task < 1000; task += 256) {
    int chunk4 = task & 3;
    int rest = task >> 2;
    int xpair = rest % 25;
    int r = rest / 25;
    int y = band * 10 + r;
    int chunk = ch0 + chunk4;
    const float* base = xg + (chunk * 8) * 2500 + y * 50 + xpair * 2;
    float2 v[8];
#pragma unroll
    for (int k = 0; k < 8; ++k) v[k] = *(const float2*)(base + k * 2500);
#pragma unroll
    for (int k = 0; k < 8; ++k)
      pm2[(chunk4 * 8 + k) * 250 + r * 25 + xpair] = fmaxf(v[k].x, v[k].y);
    uint4 a, b;
    a.x = (unsigned)bf16r(v[0].x) | ((unsigned)bf16r(v[1].x) << 16);
    a.y = (unsigned)bf16r(v[2].x) | ((unsigned)bf16r(v[3].x) << 16);
    a.z = (unsigned)bf16r(v[4].x) | ((unsigned)bf16r(v[5].x) << 16);
    a.w = (unsigned)bf16r(v[6].x) | ((unsigned)bf16r(v[7].x) << 16);
    b.x = (unsigned)bf16r(v[0].y) | ((unsigned)bf16r(v[1].y) << 16);
    b.y = (unsigned)bf16r(v[2].y) | ((unsigned)bf16r(v[3].y) << 16);
    b.z = (unsigned)bf16r(v[4].y) | ((unsigned)bf16r(v[5].y) << 16);
    b.w = (unsigned)bf16r(v[6].y) | ((unsigned)bf16r(v[7].y) << 16);
    int xx = xpair * 2;
    *(uint4*)&xsg[(((y + 1) * 52) + (xx + 1)) * 64 + chunk * 8] = a;
    *(uint4*)&xsg[(((y + 1) * 52) + (xx + 2)) * 64 + chunk * 8] = b;
  }
  uint4 z4;
  z4.x = 0; z4.y = 0; z4.z = 0; z4.w = 0;
  for (int task = tid; task < 80; task += 256) {
    int chunk4 = task & 3;
    int rest = task >> 2;
    int col = (rest & 1) ? 51 : 0;
    int r = rest >> 1;
    int y = band * 10 + r;
    *(uint4*)&xsg[(((y + 1) * 52) + col) * 64 + (ch0 + chunk4) * 8] = z4;
  }
  if (band == 0) {
    for (int task = tid; task < 208; task += 256)
      *(uint4*)&xsg[(task >> 2) * 64 + (ch0 + (task & 3)) * 8] = z4;
  }
  if (band == 4) {
    for (int task = tid; task < 208; task += 256)
      *(uint4*)&xsg[(51 * 52 + (task >> 2)) * 64 + (ch0 + (task & 3)) * 8] = z4;
  }
  __syncthreads();
  if (tid < 160) {
    int c_local = tid / 5, ox = tid % 5;
    const float* pr = &pm2[c_local * 250 + ox * 5];
    float m = -1e30f;
#pragma unroll
    for (int r = 0; r < 10; ++r) {
#pragma unroll
      for (int xp = 0; xp < 5; ++xp) m = fmaxf(m, pr[r * 25 + xp]);
    }
    int c_g = chalf * 32 + c_local;
    pooled[(size_t)g * 1600 + c_g * 25 + band * 5 + ox] = m;
  }
}

// ---- conv helper: one ik-half compute pass (FIXED swizzle t(c)=(c>>1)&3) ---
__device__ __forceinline__ void conv_pass(
    const unsigned short* in_s, const unsigned short* __restrict__ wg,
    f32x4 acc[4][4], int ikk, int wave, int lane, int l15, int l4) {
#pragma unroll
  for (int dy = 0; dy < 3; ++dy) {
    const int rr = wave + dy;
#pragma unroll
    for (int dx = 0; dx < 3; ++dx) {
      const int tap = dy * 3 + dx;
      s16x8 a[4], bfr[4];
#pragma unroll
      for (int mf = 0; mf < 4; ++mf)
        a[mf] = *reinterpret_cast<const s16x8*>(
            wg + ((((tap * 2 + ikk) * 4 + mf) * 64 + lane) << 3));
#pragma unroll
      for (int nf = 0; nf < 4; ++nf) {
        int cc = nf * 16 + l15 + dx;
        int slot = l4 ^ ((cc >> 1) & 3);   // periodic mod 8 -> conflict-free
        bfr[nf] = *reinterpret_cast<const s16x8*>(
            &in_s[((rr * 66 + cc) << 5) + (slot << 3)]);
      }
#pragma unroll
      for (int mf = 0; mf < 4; ++mf)
#pragma unroll
        for (int nf = 0; nf < 4; ++nf)
          acc[mf][nf] = __builtin_amdgcn_mfma_f32_16x16x32_bf16(
              a[mf], bfr[nf], acc[mf][nf], 0, 0, 0);
    }
  }
}

// ---- conv_main v3: ik-split DMA staging, 24.75 KB LDS ---------------------
__global__ __launch_bounds__(256, 4) void conv_main_fast2(
    const unsigned short* __restrict__ xs, const unsigned short* __restrict__ wt3,
    const float* __restrict__ fb_g, float* __restrict__ out) {
  const int g = blockIdx.x & 127;
  const int band = blockIdx.x >> 7;
  const int y0 = band * 4;
  const int tid = threadIdx.x;
  __shared__ __align__(16) unsigned short in_s[6 * 66 * 32];
  __shared__ float fb_s[64];
  if (tid < 64) fb_s[tid] = fb_g[g * 64 + tid];

  const unsigned short* xsg = xs + (size_t)g * (52 * 52 * 64);
  const unsigned short* wg = wt3 + (size_t)g * 36864;
  const int wave = tid >> 6, lane = tid & 63;
  const int l15 = lane & 15, l4 = lane >> 4;
  const int yrow = y0 + wave;

  f32x4 acc[4][4];
  f32x4 z = {0.f, 0.f, 0.f, 0.f};
#pragma unroll
  for (int mf = 0; mf < 4; ++mf)
#pragma unroll
    for (int nf = 0; nf < 4; ++nf) acc[mf][nf] = z;

  // stage ik=0
  for (int task = tid; task < 1584; task += 256) {
    int slot = task & 3;
    int c = (task >> 2) % 66;
    int r = (task >> 2) / 66;
    int py = y0 + r;
    int srcSub = slot ^ ((c >> 1) & 3);
    const unsigned short* src = xsg + ((size_t)(py * 52 + c) * 64 + srcSub * 8);
    unsigned short* ldsb = in_s + (size_t)(task & ~63) * 8;
    __builtin_amdgcn_global_load_lds(
        (const __attribute__((address_space(1))) void*)src,
        (__attribute__((address_space(3))) void*)ldsb, 16, 0, 0);
  }
  __syncthreads();
  if (yrow < 50) conv_pass(in_s, wg, acc, 0, wave, lane, l15, l4);
  __syncthreads();
  // stage ik=1
  for (int task = tid; task < 1584; task += 256) {
    int slot = task & 3;
    int c = (task >> 2) % 66;
    int r = (task >> 2) / 66;
    int py = y0 + r;
    int srcSub = slot ^ ((c >> 1) & 3);
    const unsigned short* src = xsg + ((size_t)(py * 52 + c) * 64 + 32 + srcSub * 8);
    unsigned short* ldsb = in_s + (size_t)(task & ~63) * 8;
    __builtin_amdgcn_global_load_lds(
        (const __attribute__((address_space(1))) void*)src,
        (__attribute__((address_space(3))) void*)ldsb, 16, 0, 0);
  }
  __syncthreads();
  if (yrow < 50) {
    conv_pass(in_s, wg, acc, 1, wave, lane, l15, l4);
    float* og = out + (size_t)g * 64 * 2500 + yrow * 50;
#pragma unroll
    for (int mf = 0; mf < 4; ++mf) {
#pragma unroll
      for (int r = 0; r < 4; ++r) {
        int o = mf * 16 + l4 * 4 + r;
        float fbv = fb_s[o];
#pragma unroll
        for (int nf = 0; nf < 4; ++nf) {
          int xx = nf * 16 + l15;
          if (xx < 50) og[(size_t)o * 2500 + xx] = acc[mf][nf][r] + fbv;
        }
      }
    }
  }
}

// ---- calwt: fused calibration + per-group scaled weight pack --------------
__global__ __launch_bounds__(256) void calwt_kernel(
    const float* __restrict__ avgg, const float* __restrict__ tconvw,
    const float* __restrict__ tconvb, const float* __restrict__ fcw,
    const float* __restrict__ fcb, const float* __restrict__ bias,
    const float* __restrict__ w, float* __restrict__ fb_g,
    unsigned short* __restrict__ wt3) {
  const int g = blockIdx.x;
  const int tid = threadIdx.x;
  __shared__ float tcw_s[64 * 65];
  __shared__ float av[64];
  __shared__ float sc[64];
  for (int idx = tid; idx < 4096; idx += 256)
    tcw_s[(idx >> 6) * 65 + (idx & 63)] = tconvw[idx];
  if (tid < 64) av[tid] = avgg[g * 64 + tid];
  __syncthreads();
  if (tid < 64) {
    int o = tid;
    float cal = tconvb[o];
#pragma unroll
    for (int c = 0; c < 64; ++c) cal += tcw_s[o * 65 + c] * av[c];
    sc[o] = 1.0f + cal;
    float part = fcw[o] * av[o];
#pragma unroll
    for (int off = 32; off; off >>= 1) part += __shfl_down(part, off);
    float fc = __shfl(part, 0) + fcb[0];
    fb_g[g * 64 + o] = bias[o] * (1.0f + fc);
  }
  __syncthreads();
  unsigned short* outg = wt3 + (size_t)g * 36864;
  for (int idx = tid; idx < 36864; idx += 256) {
    int j = idx & 7;
    int lane = (idx >> 3) & 63;
    int mf = (idx >> 9) & 3;
    int ik = (idx >> 11) & 1;
    int tap = idx >> 12;
    int o = mf * 16 + (lane & 15);
    int i = ik * 32 + 8 * (lane >> 4) + j;
    outg[idx] = bf16r(w[((o * 64) + i) * 9 + tap] * sc[i]);
  }
}

// ============================================================================
//              convB v2: emits scan-ready layouts (bf16 V, kk4, p28)
// ============================================================================

__device__ __forceinline__ void conv64core(const float* pool_s,
                                           const float* __restrict__ wgt,
                                           float* red, int tid) {
  int co = tid & 63, qd = tid >> 6;
  float acc[25];
#pragma unroll
  for (int n = 0; n < 25; ++n) acc[n] = 0.f;
  for (int ci = qd * 16; ci < qd * 16 + 16; ++ci) {
    float in[25];
#pragma unroll
    for (int n = 0; n < 25; ++n) in[n] = pool_s[ci * 25 + n];
    float w9[9];
#pragma unroll
    for (int tp = 0; tp < 9; ++tp) w9[tp] = wgt[(co * 64 + ci) * 9 + tp];
#pragma unroll
    for (int n = 0; n < 25; ++n) {
      int y = n / 5, xx = n % 5;
#pragma unroll
      for (int dy = 0; dy < 3; ++dy) {
        int yy = y + dy - 1;
        if (yy < 0 || yy > 4) continue;
#pragma unroll
        for (int dx = 0; dx < 3; ++dx) {
          int xc = xx + dx - 1;
          if (xc < 0 || xc > 4) continue;
          acc[n] += in[yy * 5 + xc] * w9[dy * 3 + dx];
        }
      }
    }
  }
#pragma unroll
  for (int n = 0; n < 25; ++n) red[(qd * 64 + co) * 25 + n] = acc[n];
  __syncthreads();
}

__global__ __launch_bounds__(256) void convB2_kernel(
    const float* __restrict__ pooled, const float* __restrict__ vw,
    const float* __restrict__ vb, const float* __restrict__ kw,
    const float* __restrict__ kb, const float* __restrict__ iw,
    const float* __restrict__ ib, unsigned short* __restrict__ vbg,
    float* __restrict__ kk4g, float* __restrict__ p28g) {
  const int blk = blockIdx.x;
  __shared__ float pool_s[1600];
  __shared__ float red[6400];
  const int tid = threadIdx.x;
  for (int idx = tid; idx < 1600; idx += 256) pool_s[idx] = pooled[blk * 1600 + idx];
  __syncthreads();

  // V conv -> bf16, rows padded to 40 ushorts (80B: bank-quad rotation)
  conv64core(pool_s, vw, red, tid);
  {
    unsigned short* dst = vbg + (size_t)blk * 2560;
    for (int idx = tid; idx < 1600; idx += 256) {
      float s = red[idx] + red[1600 + idx] + red[3200 + idx] + red[4800 + idx];
      dst[(idx / 25) * 40 + idx % 25] = bf16r(s + vb[idx / 25]);
    }
    for (int idx = tid; idx < 960; idx += 256)
      dst[(idx / 15) * 40 + 25 + idx % 15] = 0;
  }
  __syncthreads();

  // K conv (4 out) -> kk4g[blk*100 + m*4 + co]
  {
    int co = tid & 3, ci = tid >> 2;
    float acc[25];
#pragma unroll
    for (int n = 0; n < 25; ++n) acc[n] = 0.f;
    float in[25];
#pragma unroll
    for (int n = 0; n < 25; ++n) in[n] = pool_s[ci * 25 + n];
    float w9[9];
#pragma unroll
    for (int tp = 0; tp < 9; ++tp) w9[tp] = kw[(co * 64 + ci) * 9 + tp];
#pragma unroll
    for (int n = 0; n < 25; ++n) {
      int y = n / 5, xx = n % 5;
#pragma unroll
      for (int dy = 0; dy < 3; ++dy) {
        int yy = y + dy - 1;
        if (yy < 0 || yy > 4) continue;
#pragma unroll
        for (int dx = 0; dx < 3; ++dx) {
          int xc = xx + dx - 1;
          if (xc < 0 || xc > 4) continue;
          acc[n] += in[yy * 5 + xc] * w9[dy * 3 + dx];
        }
      }
    }
#pragma unroll
    for (int n = 0; n < 25; ++n) red[(ci * 4 + co) * 25 + n] = acc[n];
  }
  __syncthreads();
  if (tid < 100) {
    int co = tid / 25, m = tid % 25;
    float s = 0.f;
    for (int c = 0; c < 64; ++c) s += red[(c * 4 + co) * 25 + m];
    kk4g[blk * 100 + m * 4 + co] = s + kb[co];
  }
  __syncthreads();

  // prior0 -> p28 (f32, rows padded to 28; pads never read)
  if ((blk & 7) == 0) {
    conv64core(pool_s, iw, red, tid);
    float* dst = p28g + (size_t)(blk >> 3) * 1792;
    for (int idx = tid; idx < 1600; idx += 256) {
      float s = red[idx] + red[1600 + idx] + red[3200 + idx] + red[4800 + idx];
      dst[(idx / 25) * 28 + idx % 25] = s + ib[idx / 25];
    }
  }
}

// ============================================================================
//                 scan v3: bf16 V/attn, vectorized LDS traffic
// ============================================================================

__global__ __launch_bounds__(256) void scan3_kernel(
    const unsigned short* __restrict__ vbg, const float* __restrict__ kk4g,
    const float* __restrict__ p28g, const float* __restrict__ qw,
    const float* __restrict__ qb, float* __restrict__ avgg) {
  const int b = blockIdx.x;
  const int tid = threadIdx.x;
  __shared__ __align__(16) unsigned short v_bf[8 * 64 * 40];  // [l][c][m pad40]
  __shared__ __align__(16) unsigned short attn_bf[25 * 32];   // [n][m pad32]
  __shared__ float p_s[64 * 28];
  __shared__ float red[100 * 68];
  __shared__ f32x4 kk4_s[8 * 25];
  __shared__ float q_s[100];
  __shared__ float qw_s[2304];
  __shared__ float avgp[256];
  __shared__ float qb_s[4];

  // ---- preload (all b128 copies) ----
  {
    const u32x4* vs = (const u32x4*)(vbg + (size_t)b * 20480);
    u32x4* vd = (u32x4*)v_bf;
    for (int i = tid; i < 2560; i += 256) vd[i] = vs[i];
    const f32x4* ks = (const f32x4*)(kk4g + b * 800);
    for (int i = tid; i < 200; i += 256) kk4_s[i] = ks[i];
    const f32x4* ps = (const f32x4*)(p28g + (size_t)b * 1792);
    f32x4* pd = (f32x4*)p_s;
    for (int i = tid; i < 448; i += 256) pd[i] = ps[i];
    const f32x4* qs = (const f32x4*)qw;
    f32x4* qd = (f32x4*)qw_s;
    for (int i = tid; i < 576; i += 256) qd[i] = qs[i];
    if (tid < 4) qb_s[tid] = qb[tid];
  }
  __syncthreads();

  const int qco = tid & 3, qci = tid >> 2;
  float qwr[9];
#pragma unroll
  for (int tp = 0; tp < 9; ++tp) qwr[tp] = qw_s[(qco * 64 + qci) * 9 + tp];

#pragma unroll 1
  for (int l = 0; l < 8; ++l) {
    // ---- P1: q-conv partials (b128 p reads) + off-path avg store ----
    {
      f32x4 i4[7];
      const f32x4* pr = (const f32x4*)&p_s[qci * 28];
#pragma unroll
      for (int j = 0; j < 7; ++j) i4[j] = pr[j];
      float in[25];
#pragma unroll
      for (int n = 0; n < 25; ++n) in[n] = i4[n >> 2][n & 3];
      float acc[25];
#pragma unroll
      for (int n = 0; n < 25; ++n) acc[n] = 0.f;
#pragma unroll
      for (int n = 0; n < 25; ++n) {
        int y = n / 5, xx = n % 5;
#pragma unroll
        for (int dy = 0; dy < 3; ++dy) {
          int yy = y + dy - 1;
          if (yy < 0 || yy > 4) continue;
#pragma unroll
          for (int dx = 0; dx < 3; ++dx) {
            int xc = xx + dx - 1;
            if (xc < 0 || xc > 4) continue;
            acc[n] += in[yy * 5 + xc] * qwr[dy * 3 + dx];
          }
        }
      }
#pragma unroll
      for (int n = 0; n < 25; ++n) red[(qco * 25 + n) * 68 + qci] = acc[n];
    }
    if (l > 0 && tid < 64) {
      f32x4 a4 = *(const f32x4*)&avgp[tid * 4];
      avgg[(b * 8 + l - 1) * 64 + tid] = (a4[0] + a4[1] + a4[2] + a4[3]) * 0.04f;
    }
    __syncthreads();

    // ---- P2: reduce 64 ci partials -> q_s ----
    if (tid < 200) {
      int row = tid >> 1, h = tid & 1;
      const f32x4* rp = (const f32x4*)&red[row * 68 + h * 32];
      float s = 0.f;
#pragma unroll
      for (int j = 0; j < 8; ++j) {
        f32x4 r4 = rp[j];
        s += r4[0] + r4[1] + r4[2] + r4[3];
      }
      s += __shfl_down(s, 1);
      if (h == 0) q_s[row] = s + qb_s[row / 25];
    }
    __syncthreads();

    // ---- P3: qk + softmax in registers, pack attn row to bf16 ----
    if (tid < 25) {
      const int n = tid;
      const f32x4* kk = &kk4_s[l * 25];
      float q0 = q_s[n], q1 = q_s[25 + n], q2 = q_s[50 + n], q3 = q_s[75 + n];
      float row[25];
      float mx = -1e30f;
#pragma unroll
      for (int m = 0; m < 25; ++m) {
        f32x4 k4 = kk[m];
        float s = q0 * k4[0] + q1 * k4[1] + q2 * k4[2] + q3 * k4[3];
        row[m] = s;
        mx = fmaxf(mx, s);
      }
      float sm = 0.f;
#pragma unroll
      for (int m = 0; m < 25; ++m) {
        float e = __expf(row[m] - mx);
        row[m] = e;
        sm += e;
      }
      float inv = 1.0f / sm;
      unsigned int w16[16];
#pragma unroll
      for (int j = 0; j < 16; ++j) {
        float lo = (2 * j < 25) ? row[2 * j] * inv : 0.f;
        float hi = (2 * j + 1 < 25) ? row[2 * j + 1] * inv : 0.f;
        w16[j] = (unsigned)bf16r(lo) | ((unsigned)bf16r(hi) << 16);
      }
      u32x4* ad = (u32x4*)&attn_bf[n * 32];
      u32x4 d0 = {w16[0], w16[1], w16[2], w16[3]};
      u32x4 d1 = {w16[4], w16[5], w16[6], w16[7]};
      u32x4 d2 = {w16[8], w16[9], w16[10], w16[11]};
      u32x4 d3 = {w16[12], w16[13], w16[14], w16[15]};
      ad[0] = d0; ad[1] = d1; ad[2] = d2; ad[3] = d3;
    }
    __syncthreads();

    // ---- P4: pv (bf16 v x bf16 attn, fp32 accum) + avg partials ----
    {
      const int c = tid & 63, grp = tid >> 6;
      const u32x4* vr = (const u32x4*)&v_bf[(l * 64 + c) * 40];
      u32x4 vv[4];
#pragma unroll
      for (int j = 0; j < 4; ++j) vv[j] = vr[j];
      float vf[25];
#pragma unroll
      for (int m = 0; m < 25; ++m) {
        unsigned int u = vv[m >> 3][(m >> 1) & 3];
        vf[m] = (m & 1) ? bf_hi(u) : bf_lo(u);
      }
      float partial = 0.f;
      for (int n = grp; n < 25; n += 4) {
        const u32x4* ar = (const u32x4*)&attn_bf[n * 32];
        u32x4 aa[4];
#pragma unroll
        for (int j = 0; j < 4; ++j) aa[j] = ar[j];
        float acc = 0.f;
#pragma unroll
        for (int m = 0; m < 25; ++m) {
          unsigned int u = aa[m >> 3][(m >> 1) & 3];
          float a = (m & 1) ? bf_hi(u) : bf_lo(u);
          acc += vf[m] * a;
        }
        p_s[c * 28 + n] = acc;
        partial += acc;
      }
      avgp[(c << 2) + grp] = partial;
    }
    __syncthreads();
  }
  if (tid < 64) {
    f32x4 a4 = *(const f32x4*)&avgp[tid * 4];
    avgg[(b * 8 + 7) * 64 + tid] = (a4[0] + a4[1] + a4[2] + a4[3]) * 0.04f;
  }
}

// ============================================================================
//                       LEGACY PATH — fallback only
// ============================================================================

__global__ __launch_bounds__(256) void pool_kernel(const float* __restrict__ x,
                                                   float* __restrict__ pooled) {
  const int blk = blockIdx.x;
  const float* plane = x + (size_t)blk * 2500;
  __shared__ float pmax[250];
  const int t = threadIdx.x;
  if (t < 250) {
    int r = t / 5, cc = t % 5;
    const float* row = plane + r * 50 + cc * 10;
    float m = row[0];
#pragma unroll
    for (int j = 1; j < 10; ++j) m = fmaxf(m, row[j]);
    pmax[r * 5 + cc] = m;
  }
  __syncthreads();
  if (t < 25) {
    int pr = t / 5, cc = t % 5;
    float m = pmax[(pr * 10) * 5 + cc];
#pragma unroll
    for (int rr = 1; rr < 10; ++rr) m = fmaxf(m, pmax[(pr * 10 + rr) * 5 + cc]);
    pooled[(size_t)blk * 25 + t] = m;
  }
}

__global__ __launch_bounds__(256) void wt_kernel(const float* __restrict__ w,
                                                 unsigned short* __restrict__ wt2) {
  int idx = blockIdx.x * 256 + threadIdx.x;
  if (idx >= 36864) return;
  int j = idx & 7;
  int lane = (idx >> 3) & 63;
  int mf = (idx >> 9) & 3;
  int ik = (idx >> 11) & 1;
  int tap = idx >> 12;
  int o = mf * 16 + (lane & 15);
  int i = ik * 32 + 8 * (lane >> 4) + j;
  wt2[idx] = bf16r(w[((o * 64) + i) * 9 + tap]);
}

__global__ __launch_bounds__(256) void conv_main(
    const float* __restrict__ x, const unsigned short* __restrict__ wt2,
    const float* __restrict__ scale_g, const float* __restrict__ fb_g,
    float* __restrict__ out) {
  const int g = blockIdx.x & 127;
  const int band = blockIdx.x >> 7;
  const int y0 = band * 4;
  const int tid = threadIdx.x;
  __shared__ unsigned short in_s[6 * 66 * 64];
  __shared__ float scale_s[64], fb_s[64];
  if (tid < 64) {
    scale_s[tid] = scale_g[g * 64 + tid];
    fb_s[tid] = fb_g[g * 64 + tid];
  }
  __syncthreads();
  const float* xg = x + (size_t)g * 160000;
  for (int task = tid; task < 3168; task += 256) {
    int c = task % 66;
    int rc = task / 66;
    int r = rc >> 3;
    int chunk = rc & 7;
    int y = y0 - 1 + r;
    int xi = c - 1;
    unsigned int p0 = 0, p1 = 0, p2 = 0, p3 = 0;
    if (y >= 0 && y < 50 && xi >= 0 && xi < 50) {
      const float* px = xg + chunk * 8 * 2500 + y * 50 + xi;
      float f0 = px[0] * scale_s[chunk * 8 + 0];
      float f1 = px[2500] * scale_s[chunk * 8 + 1];
      float f2 = px[5000] * scale_s[chunk * 8 + 2];
      float f3 = px[7500] * scale_s[chunk * 8 + 3];
      float f4 = px[10000] * scale_s[chunk * 8 + 4];
      float f5 = px[12500] * scale_s[chunk * 8 + 5];
      float f6 = px[15000] * scale_s[chunk * 8 + 6];
      float f7 = px[17500] * scale_s[chunk * 8 + 7];
      p0 = (unsigned)bf16r(f0) | ((unsigned)bf16r(f1) << 16);
      p1 = (unsigned)bf16r(f2) | ((unsigned)bf16r(f3) << 16);
      p2 = (unsigned)bf16r(f4) | ((unsigned)bf16r(f5) << 16);
      p3 = (unsigned)bf16r(f6) | ((unsigned)bf16r(f7) << 16);
    }
    int chS = chunk ^ (c & 7);
    uint4* dst = (uint4*)&in_s[((r * 66 + c) << 6) + (chS << 3)];
    uint4 u4;
    u4.x = p0; u4.y = p1; u4.z = p2; u4.w = p3;
    *dst = u4;
  }
  __syncthreads();
  const int wave = tid >> 6, lane = tid & 63;
  const int l15 = lane & 15, l4 = lane >> 4;
  const int yrow = y0 + wave;
  if (yrow < 50) {
    f32x4 acc[4][4];
    f32x4 z = {0.f, 0.f, 0.f, 0.f};
#pragma unroll
    for (int mf = 0; mf < 4; ++mf)
#pragma unroll
      for (int nf = 0; nf < 4; ++nf) acc[mf][nf] = z;
#pragma unroll
    for (int dy = 0; dy < 3; ++dy) {
      const int rr = wave + dy;
#pragma unroll
      for (int dx = 0; dx < 3; ++dx) {
        const int tap = dy * 3 + dx;
#pragma unroll
        for (int ik = 0; ik < 2; ++ik) {
          s16x8 a[4], bfr[4];
#pragma unroll
          for (int mf = 0; mf < 4; ++mf)
            a[mf] = *reinterpret_cast<const s16x8*>(
                wt2 + ((((tap * 2 + ik) * 4 + mf) * 64 + lane) << 3));
#pragma unroll
          for (int nf = 0; nf < 4; ++nf) {
            int cc = nf * 16 + l15 + dx;
            int chS = (ik * 4 + l4) ^ (cc & 7);
            bfr[nf] = *reinterpret_cast<const s16x8*>(
                &in_s[((rr * 66 + cc) << 6) + (chS << 3)]);
          }
#pragma unroll
          for (int mf = 0; mf < 4; ++mf)
#pragma unroll
            for (int nf = 0; nf < 4; ++nf)
              acc[mf][nf] = __builtin_amdgcn_mfma_f32_16x16x32_bf16(
                  a[mf], bfr[nf], acc[mf][nf], 0, 0, 0);
        }
      }
    }
    float* og = out + (size_t)g * 64 * 2500 + yrow * 50;
#pragma unroll
    for (int mf = 0; mf < 4; ++mf) {
#pragma unroll
      for (int r = 0; r < 4; ++r) {
        int o = mf * 16 + l4 * 4 + r;
        float fbv = fb_s[o];
#pragma unroll
        for (int nf = 0; nf < 4; ++nf) {
          int xx = nf * 16 + l15;
          if (xx < 50) og[(size_t)o * 2500 + xx] = acc[mf][nf][r] + fbv;
        }
      }
    }
  }
}

__global__ __launch_bounds__(256) void calib_kernel(
    const float* __restrict__ avgg, const float* __restrict__ tconvw,
    const float* __restrict__ tconvb, const float* __restrict__ fcw,
    const float* __restrict__ fcb, const float* __restrict__ bias,
    float* __restrict__ scale_g, float* __restrict__ fb_g) {
  const int tid = threadIdx.x;
  const int wave = tid >> 6, o = tid & 63;
  const int bl = blockIdx.x * 4 + wave;
  __shared__ float tcw_s[64 * 65];
  __shared__ float avgl[4][64];
  for (int idx = tid; idx < 4096; idx += 256)
    tcw_s[(idx >> 6) * 65 + (idx & 63)] = tconvw[idx];
  avgl[wave][o] = avgg[bl * 64 + o];
  __syncthreads();
  float cal = tconvb[o];
  const float* av = avgl[wave];
#pragma unroll
  for (int c = 0; c < 64; ++c) cal += tcw_s[o * 65 + c] * av[c];
  scale_g[bl * 64 + o] = 1.0f + cal;
  float part = fcw[o] * av[o];
#pragma unroll
  for (int off = 32; off; off >>= 1) part += __shfl_down(part, off);
  float fc = __shfl(part, 0) + fcb[0];
  fb_g[bl * 64 + o] = bias[o] * (1.0f + fc);
}

// --------------------------------- launch ---------------------------------
extern "C" void kernel_launch(void* const* d_in, const int* in_sizes, int n_in,
                              void* d_out, int out_size, void* d_ws, size_t ws_size,
                              hipStream_t stream) {
  const float* x       = (const float*)d_in[0];
  const float* weight  = (const float*)d_in[1];
  const float* bias    = (const float*)d_in[2];
  const float* init_w  = (const float*)d_in[3];
  const float* init_b  = (const float*)d_in[4];
  const float* q_w     = (const float*)d_in[5];
  const float* q_b     = (const float*)d_in[6];
  const float* k_w     = (const float*)d_in[7];
  const float* k_b     = (const float*)d_in[8];
  const float* v_w     = (const float*)d_in[9];
  const float* v_b     = (const float*)d_in[10];
  const float* tconv_w = (const float*)d_in[11];
  const float* tconv_b = (const float*)d_in[12];
  const float* fc_w    = (const float*)d_in[13];
  const float* fc_b    = (const float*)d_in[14];
  float* out = (float*)d_out;

  float* ws = (float*)d_ws;
  float* pooled = ws;                                      // 204800 f
  unsigned short* vbg = (unsigned short*)(ws + 204800);    // 327680 us = 163840 f
  float* kk4g   = ws + 368640;                             // 12800 f
  float* p28g   = ws + 381440;                             // 28672 f
  float* scaleg = ws + 410112;                             // 8192 f (legacy)
  float* fbg    = ws + 418304;                             // 8192 f
  float* avgg   = ws + 426496;                             // 8192 f
  unsigned short* wt3 = (unsigned short*)(ws + 434688);    // 4718592 us
  unsigned short* xsb = wt3 + 4718592;                     // 22151168 us

  const size_t NEED_FAST = 55543808ull;  // buffers + 64KB OOB slack

  if (ws_size >= NEED_FAST) {
    poolprep2_kernel<<<1280, 256, 0, stream>>>(x, pooled, xsb);
    convB2_kernel<<<128, 256, 0, stream>>>(pooled, v_w, v_b, k_w, k_b, init_w,
                                           init_b, vbg, kk4g, p28g);
    scan3_kernel<<<16, 256, 0, stream>>>(vbg, kk4g, p28g, q_w, q_b, avgg);
    calwt_kernel<<<128, 256, 0, stream>>>(avgg, tconv_w, tconv_b, fc_w, fc_b, bias,
                                          weight, fbg, wt3);
    conv_main_fast2<<<13 * 128, 256, 0, stream>>>(xsb, wt3, fbg, out);
  } else {
    unsigned short* wt2 = (unsigned short*)(ws + 434688);
    pool_kernel<<<8192, 256, 0, stream>>>(x, pooled);
    wt_kernel<<<144, 256, 0, stream>>>(weight, wt2);
    convB2_kernel<<<128, 256, 0, stream>>>(pooled, v_w, v_b, k_w, k_b, init_w,
                                           init_b, vbg, kk4g, p28g);
    scan3_kernel<<<16, 256, 0, stream>>>(vbg, kk4g, p28g, q_w, q_b, avgg);
    calib_kernel<<<32, 256, 0, stream>>>(avgg, tconv_w, tconv_b, fc_w, fc_b, bias,
                                         scaleg, fbg);
    conv_main<<<13 * 128, 256, 0, stream>>>(x, wt2, scaleg, fbg, out);
  }
}